// Round 3
// baseline (248.491 us; speedup 1.0000x reference)
//
#include <hip/hip_runtime.h>
#include <hip/hip_bf16.h>

typedef unsigned short u16;
typedef unsigned int   u32;
typedef short   bf16x8 __attribute__((ext_vector_type(8)));  // bf16 carried as i16
typedef float   f32x4  __attribute__((ext_vector_type(4)));

__device__ __forceinline__ float bf2f(u16 u) {
    u32 t = ((u32)u) << 16;
    return __builtin_bit_cast(float, t);
}
__device__ __forceinline__ u32 f2bf(float f) {
    u32 u = __builtin_bit_cast(u32, f);
    return (u + 0x7FFFu + ((u >> 16) & 1u)) >> 16;   // RNE
}
// async global->LDS DMA, 16 B per lane (dst = wave-uniform base + lane*16)
__device__ __forceinline__ void load_lds16(const u16* g, u16* l) {
    __builtin_amdgcn_global_load_lds(
        (const __attribute__((address_space(1))) u32*)(const void*)g,
        (__attribute__((address_space(3))) u32*)(void*)l, 16, 0, 0);
}
// Inline-asm loads (saddr form): compiler cannot sink these or auto-wait on
// them -> true async issue. We pair them with a manual vmcnt (rule #18).
__device__ __forceinline__ float gload(const float* sbase, u32 voff) {
    float r;
    asm volatile("global_load_dword %0, %1, %2"
                 : "=v"(r) : "v"(voff), "s"(sbase) : "memory");
    return r;
}
__device__ __forceinline__ uint4 gload4(const u16* sbase, u32 voff) {
    uint4 r;
    asm volatile("global_load_dwordx4 %0, %1, %2"
                 : "=v"(r) : "v"(voff), "s"(sbase) : "memory");
    return r;
}
#define WAITVM(N) do { asm volatile("s_waitcnt vmcnt(" #N ")" ::: "memory"); \
                       __builtin_amdgcn_sched_barrier(0); } while (0)

// ---------------------------------------------------------------------------
// GLOBAL K-ORDER (both GEMMs): r = t*256 + c  (tap-major).
// ---------------------------------------------------------------------------

// Kernel 0a: offset/mask conv weights -> hi/lo bf16 A[32][2304], r = t*256+c
__global__ void kprep(const float* __restrict__ woff, const float* __restrict__ wmod,
                      u16* __restrict__ ah, u16* __restrict__ al) {
    int i = blockIdx.x * 256 + threadIdx.x;      // 288 blocks -> 73728 exact
    if (i >= 32 * 2304) return;
    int oc = i / 2304, r = i - oc * 2304;
    int t = r >> 8, c = r & 255;
    float v = 0.f;
    if (oc < 18)      v = woff[oc * 2304 + c * 9 + t];
    else if (oc < 27) v = wmod[(oc - 18) * 2304 + c * 9 + t];
    u32 hb = f2bf(v);
    u32 lb = f2bf(v - bf2f((u16)hb));
    ah[i] = (u16)hb;
    al[i] = (u16)lb;
}

// Kernel 0b: w_reg f32 -> bf16, layout [o][t*256+c] (matches gather K-order).
__global__ void kwreg(const float* __restrict__ wreg, u16* __restrict__ wregb) {
    int i = blockIdx.x * 256 + threadIdx.x;      // 2304 blocks exact
    int o = i / 2304, r = i - o * 2304;
    int t = r >> 8, c = r & 255;
    wregb[i] = (u16)f2bf(wreg[o * 2304 + c * 9 + t]);
}

// ---------------------------------------------------------------------------
// Kernel 1: offset/mask conv as MFMA GEMM, M=32 (27 live), N=16384, K=2304.
// hi/lo bf16 split on both operands -> 3 MFMAs, fp32-equivalent precision.
// PIPELINED via inline-asm loads: issue 10 loads(kt+1) -> MFMA(kt) ->
// vmcnt(0) -> convert+LDS-write -> one barrier per kt. Compiler cannot sink
// the asm loads, so latency truly hides under the MFMA phase.
// ---------------------------------------------------------------------------
__global__ __launch_bounds__(256) void koffg(const float* __restrict__ x,
                                             const u16* __restrict__ ah_g,
                                             const u16* __restrict__ al_g,
                                             const float* __restrict__ boff,
                                             const float* __restrict__ bmod,
                                             float* __restrict__ offf) {
    __shared__ u16 Ah[2][32 * 72], Al[2][32 * 72]; // 32 oc-rows, 64 k + 8 pad
    __shared__ u16 Bh[2][32 * 72], Bl[2][32 * 72]; // 32 n-rows,  64 k + 8 pad
    int tid = threadIdx.x;
    int n0 = blockIdx.x * 32;
    int b = n0 >> 12, h0 = (n0 & 4095) >> 6, w0 = n0 & 63;
    int lane = tid & 63, wv = tid >> 6;
    int mt = wv & 1, nt = wv >> 1;               // 2 m-tiles x 2 n-tiles of 16
    int col = lane & 15, quad = lane >> 4;

    int aoc = tid >> 3, ak0 = (tid & 7) * 8;     // A staging role
    int nl = tid & 31, cl0 = (tid >> 5) * 8;     // B staging role

    const float* xb = x + ((long)b << 20);       // image base (SGPR)
    u32 avoff0 = (u32)(aoc * 2304 + ak0) * 2;    // bytes into ah_g/al_g

    f32x4 acc = (f32x4){0.f, 0.f, 0.f, 0.f};

    uint4 pah, pal;
    float xv[8];
    bool  vm;

    auto issue = [&](int kt) {                   // 10 asm loads, stay in flight
        int t = kt >> 2, c0 = (kt & 3) << 6, r0 = kt * 64;
        int dy = t / 3 - 1, dx = t % 3 - 1;
        pah = gload4(ah_g, avoff0 + (u32)r0 * 2);
        pal = gload4(al_g, avoff0 + (u32)r0 * 2);
        int hp = h0 + dy, wp = w0 + nl + dx;
        vm = ((unsigned)hp < 64u) && ((unsigned)wp < 64u);
        int hc = min(max(hp, 0), 63), wc = min(max(wp, 0), 63);
        u32 pix4 = (u32)(hc * 64 + wc) * 4;
#pragma unroll
        for (int i = 0; i < 8; i++)
            xv[i] = gload(xb, ((u32)(c0 + cl0 + i) << 14) + pix4);
    };
    auto stores = [&](int buf) {                 // after WAITVM(0)
        u32 whi[4], wlo[4];
#pragma unroll
        for (int i = 0; i < 8; i++) {
            float v = vm ? xv[i] : 0.f;
            u32 hb = f2bf(v);
            u32 lb = f2bf(v - bf2f((u16)hb));
            if (i & 1) { whi[i >> 1] |= hb << 16; wlo[i >> 1] |= lb << 16; }
            else       { whi[i >> 1]  = hb;       wlo[i >> 1]  = lb; }
        }
        *(uint4*)&Ah[buf][aoc * 72 + ak0] = pah;
        *(uint4*)&Al[buf][aoc * 72 + ak0] = pal;
        *(uint4*)&Bh[buf][nl * 72 + cl0] = make_uint4(whi[0], whi[1], whi[2], whi[3]);
        *(uint4*)&Bl[buf][nl * 72 + cl0] = make_uint4(wlo[0], wlo[1], wlo[2], wlo[3]);
    };

    issue(0);
    WAITVM(0);
    stores(0);
    __syncthreads();

    for (int kt = 0; kt < 36; kt++) {
        int cur = kt & 1, nxt = kt + 1;
        if (nxt < 36) issue(nxt);                // in flight over MFMA phase
#pragma unroll
        for (int ks = 0; ks < 2; ks++) {
            int ko = ks * 32 + quad * 8;
            bf16x8 fah = *(const bf16x8*)&Ah[cur][(mt * 16 + col) * 72 + ko];
            bf16x8 fal = *(const bf16x8*)&Al[cur][(mt * 16 + col) * 72 + ko];
            bf16x8 fbh = *(const bf16x8*)&Bh[cur][(nt * 16 + col) * 72 + ko];
            bf16x8 fbl = *(const bf16x8*)&Bl[cur][(nt * 16 + col) * 72 + ko];
            acc = __builtin_amdgcn_mfma_f32_16x16x32_bf16(fah, fbh, acc, 0, 0, 0);
            acc = __builtin_amdgcn_mfma_f32_16x16x32_bf16(fah, fbl, acc, 0, 0, 0);
            acc = __builtin_amdgcn_mfma_f32_16x16x32_bf16(fal, fbh, acc, 0, 0, 0);
        }
        if (nxt < 36) {
            WAITVM(0);                           // gathers done; latency hidden
            stores(nxt & 1);
        }
        __syncthreads();                         // one barrier per kt
    }

    int n = n0 + nt * 16 + col;
#pragma unroll
    for (int r = 0; r < 4; r++) {
        int oc = mt * 16 + quad * 4 + r;
        float s = acc[r];
        if (oc < 18) {
            int ch = 3 * (oc >> 1) + (oc & 1);   // even oc -> dy, odd -> dx
            offf[(ch << 14) + n] = s + boff[oc];
        } else if (oc < 27) {
            float tt = s + bmod[oc - 18];
            int ch = 3 * (oc - 18) + 2;
            offf[(ch << 14) + n] = 2.f / (1.f + __expf(-tt));
        }
    }
}

// ---------------------------------------------------------------------------
// Kernel 2 (FUSED, HARD-PIPELINED): sampling + GEMM + BN + ReLU.
// Block = 64 pixels x 256 outputs, 512 thr, 8 waves, grid 256 (1 block/CU).
// Per kt: issue 32 asm gathers(kt+1) + 4 A-DMAs(kt+1) -> MFMA(kt) ->
// vmcnt(4) (gathers are the 32 oldest; DMAs drain at the barrier) ->
// weight/pack/ds_write -> ONE barrier. Double-buffered LDS (80 KB).
// ---------------------------------------------------------------------------
__global__ __launch_bounds__(512, 2) void kfused(const float* __restrict__ x,
                                                 const float* __restrict__ offf,
                                                 const u16* __restrict__ wregb,
                                                 const float* __restrict__ gamma,
                                                 const float* __restrict__ beta,
                                                 const float* __restrict__ rmean,
                                                 const float* __restrict__ rvar,
                                                 float* __restrict__ out) {
    __shared__ u16 Wl[2][256 * 64];  // [buf][o][k] granule-XOR-swizzled, 64 KB
    __shared__ u16 Sl[2][8 * 64 * 8];// [buf][c-octet][n][8ch], 16 KB
    int tid = threadIdx.x;
    int lane = tid & 63, wv = tid >> 6;
    int nl = lane, og = wv;                      // pixel-in-block, channel octet
    int bb = blockIdx.x >> 6;                    // image   (block-uniform)
    int h  = blockIdx.x & 63;                    // row     (block-uniform)
    int n  = blockIdx.x * 64 + nl;               // global pixel id
    int wo = (wv >> 1) * 64, wn = (wv & 1) * 32; // wave output tile 64o x 32n
    int col = lane & 15, quad = lane >> 4;

    const float* xb = x + ((long)bb << 20);      // image base (SGPR)

    f32x4 acc[4][2];
#pragma unroll
    for (int i = 0; i < 4; i++)
#pragma unroll
        for (int j = 0; j < 2; j++) acc[i][j] = (f32x4){0.f, 0.f, 0.f, 0.f};

    u32   v00 = 0, v01 = 0, v10 = 0, v11 = 0;    // neighbor byte offsets
    float s00 = 0.f, s01 = 0.f, s10 = 0.f, s11 = 0.f;
    float g00[8], g01[8], g10[8], g11[8];        // in-flight gather values

    auto tapst = [&](int t) {                    // rebuild tap state (every 4 kt)
        int g = t / 3, tx = t - 3 * g;
        float dy = offf[((3 * t + 0) << 14) + n];
        float dx = offf[((3 * t + 1) << 14) + n];
        float m  = offf[((3 * t + 2) << 14) + n];
        float py = (float)(h - 1 + g) + dy;
        float px = (float)(nl - 1 + tx) + dx;
        float y0f = floorf(py), x0f = floorf(px);
        float wy = py - y0f, wx = px - x0f;
        int iy0 = (int)y0f, ix0 = (int)x0f;
        int iy1 = iy0 + 1, ix1 = ix0 + 1;
        bool vy0 = (unsigned)iy0 < 64u, vy1 = (unsigned)iy1 < 64u;
        bool vx0 = (unsigned)ix0 < 64u, vx1 = (unsigned)ix1 < 64u;
        int cy0 = min(max(iy0, 0), 63), cy1 = min(max(iy1, 0), 63);
        int cx0 = min(max(ix0, 0), 63), cx1 = min(max(ix1, 0), 63);
        v00 = (u32)(cy0 * 64 + cx0) * 4; v01 = (u32)(cy0 * 64 + cx1) * 4;
        v10 = (u32)(cy1 * 64 + cx0) * 4; v11 = (u32)(cy1 * 64 + cx1) * 4;
        float a = 1.f - wy, bw = 1.f - wx;
        s00 = (vy0 && vx0) ? a  * bw * m : 0.f;
        s01 = (vy0 && vx1) ? a  * wx * m : 0.f;
        s10 = (vy1 && vx0) ? wy * bw * m : 0.f;
        s11 = (vy1 && vx1) ? wy * wx * m : 0.f;
    };
    auto gissue = [&](int kt) {                  // 32 asm gathers, in flight
        u32 cb = (u32)(og * 8 + ((kt & 3) << 6)) << 14;  // channel byte base
#pragma unroll
        for (int cc = 0; cc < 8; cc++) {
            u32 co = cb + ((u32)cc << 14);
            g00[cc] = gload(xb, co + v00);
            g01[cc] = gload(xb, co + v01);
            g10[cc] = gload(xb, co + v10);
            g11[cc] = gload(xb, co + v11);
        }
    };
    auto dmaA = [&](int kt, int buf) {           // async A staging, 32 KB
#pragma unroll
        for (int i = 0; i < 4; i++) {
            int cidx = tid + i * 512;
            int o = cidx >> 3, qp = cidx & 7;
            int ql = qp ^ (o & 7);               // source-side XOR swizzle
            load_lds16(wregb + (long)o * 2304 + kt * 64 + ql * 8,
                       &Wl[buf][cidx * 8]);
        }
    };
    auto bwrite = [&](int buf) {                 // after WAITVM: weight+pack+write
        u32 wd[4];
#pragma unroll
        for (int cc = 0; cc < 8; cc++) {
            float v = s00 * g00[cc] + s01 * g01[cc] +
                      s10 * g10[cc] + s11 * g11[cc];
            u32 bv = f2bf(v);
            if (cc & 1) wd[cc >> 1] |= bv << 16;
            else        wd[cc >> 1]  = bv;
        }
        *(uint4*)&Sl[buf][(og * 64 + nl) * 8] =
            make_uint4(wd[0], wd[1], wd[2], wd[3]);
    };

    // prologue: fill buffer 0
    tapst(0);
    gissue(0);
    dmaA(0, 0);
    WAITVM(0);
    bwrite(0);
    __syncthreads();

    for (int kt = 0; kt < 36; kt++) {
        int cur = kt & 1, nxt = kt + 1;
        if (nxt < 36) {
            if ((nxt & 3) == 0) tapst(nxt >> 2);
            gissue(nxt);                         // 32 oldest outstanding vmem
            dmaA(nxt, nxt & 1);                  // 4 newest (drain at barrier)
        }
#pragma unroll
        for (int ks = 0; ks < 2; ks++) {
            bf16x8 af[4], bfr[2];
#pragma unroll
            for (int i = 0; i < 4; i++) {
                int r = wo + i * 16 + col;
                int ph = (ks * 4 + quad) ^ (r & 7);
                af[i] = *(const bf16x8*)&Wl[cur][r * 64 + ph * 8];
            }
#pragma unroll
            for (int j = 0; j < 2; j++)
                bfr[j] = *(const bf16x8*)&Sl[cur][((ks * 4 + quad) * 64 +
                                                   (wn + j * 16 + col)) * 8];
#pragma unroll
            for (int i = 0; i < 4; i++)
#pragma unroll
                for (int j = 0; j < 2; j++)
                    acc[i][j] = __builtin_amdgcn_mfma_f32_16x16x32_bf16(
                        af[i], bfr[j], acc[i][j], 0, 0, 0);
        }
        if (nxt < 36) {
            WAITVM(4);                           // gathers done, DMA may fly
            bwrite(nxt & 1);
        }
        __syncthreads();                         // drains DMA + ds_write; one/kt
    }

    // epilogue: BN + ReLU, D layout: row(o) = quad*4+reg, col(n) = lane&15
#pragma unroll
    for (int i = 0; i < 4; i++) {
        int ob = wo + i * 16 + quad * 4;
        float inv[4], add[4];
#pragma unroll
        for (int r = 0; r < 4; r++) {
            int o = ob + r;
            float iv = gamma[o] * rsqrtf(rvar[o] + 1e-5f);
            inv[r] = iv; add[r] = beta[o] - rmean[o] * iv;
        }
#pragma unroll
        for (int j = 0; j < 2; j++) {
            int n_g = blockIdx.x * 64 + wn + j * 16 + col;
            int bq = n_g >> 12, hw = n_g & 4095;
            float* op = out + ((long)bq << 20) + hw;
#pragma unroll
            for (int r = 0; r < 4; r++) {
                float v = acc[i][j][r] * inv[r] + add[r];
                v = fmaxf(v, 0.f);
                op[(long)(ob + r) << 12] = v;
            }
        }
    }
}

// ---------------------------------------------------------------------------
extern "C" void kernel_launch(void* const* d_in, const int* in_sizes, int n_in,
                              void* d_out, int out_size, void* d_ws, size_t ws_size,
                              hipStream_t stream) {
    const float* x     = (const float*)d_in[0];
    const float* woff  = (const float*)d_in[1];
    const float* boff  = (const float*)d_in[2];
    const float* wmod  = (const float*)d_in[3];
    const float* bmod  = (const float*)d_in[4];
    const float* wreg  = (const float*)d_in[5];
    const float* gamma = (const float*)d_in[6];
    const float* beta  = (const float*)d_in[7];
    const float* rmean = (const float*)d_in[8];
    const float* rvar  = (const float*)d_in[9];
    float* out = (float*)d_out;

    char* ws = (char*)d_ws;
    // ws map:
    //   [0x000000, 0x024000) wph   bf16  144 KB (A hi, koffg)
    //   [0x040000, 0x064000) wpl   bf16  144 KB (A lo)
    //   [0x080000, 0x23C000) offf  fp32  1.77 MB
    //   [0x240000, 0x360000) wregb bf16  1.18 MB ([o][t*256+c] order)
    u16*   wph   = (u16*)(ws);
    u16*   wpl   = (u16*)(ws + 0x40000u);
    float* offf  = (float*)(ws + 0x80000u);
    u16*   wregb = (u16*)(ws + 0x240000u);

    kprep<<<288,  256, 0, stream>>>(woff, wmod, wph, wpl);
    kwreg<<<2304, 256, 0, stream>>>(wreg, wregb);
    koffg<<<512,  256, 0, stream>>>(x, wph, wpl, boff, bmod, offf);
    kfused<<<256, 512, 0, stream>>>(x, offf, wregb, gamma, beta,
                                    rmean, rvar, out);
}

// Round 6
// 242.172 us; speedup vs baseline: 1.0261x; 1.0261x over previous
//
#include <hip/hip_runtime.h>
#include <hip/hip_bf16.h>

typedef unsigned short u16;
typedef unsigned int   u32;
typedef short   bf16x8 __attribute__((ext_vector_type(8)));  // bf16 carried as i16
typedef float   f32x4  __attribute__((ext_vector_type(4)));

__device__ __forceinline__ float bf2f(u16 u) {
    u32 t = ((u32)u) << 16;
    return __builtin_bit_cast(float, t);
}
__device__ __forceinline__ u32 f2bf(float f) {
    u32 u = __builtin_bit_cast(u32, f);
    return (u + 0x7FFFu + ((u >> 16) & 1u)) >> 16;   // RNE
}
// async global->LDS DMA, 16 B per lane (dst = wave-uniform base + lane*16)
__device__ __forceinline__ void load_lds16(const u16* g, u16* l) {
    __builtin_amdgcn_global_load_lds(
        (const __attribute__((address_space(1))) u32*)(const void*)g,
        (__attribute__((address_space(3))) u32*)(void*)l, 16, 0, 0);
}
// Inline-asm loads (saddr form): compiler cannot sink these or auto-wait on
// them -> true async issue. We pair them with a manual vmcnt (rule #18).
__device__ __forceinline__ float gload(const float* sbase, u32 voff) {
    float r;
    asm volatile("global_load_dword %0, %1, %2"
                 : "=v"(r) : "v"(voff), "s"(sbase) : "memory");
    return r;
}
__device__ __forceinline__ uint4 gload4(const u16* sbase, u32 voff) {
    uint4 r;
    asm volatile("global_load_dwordx4 %0, %1, %2"
                 : "=v"(r) : "v"(voff), "s"(sbase) : "memory");
    return r;
}
#define WAITVM(N) do { asm volatile("s_waitcnt vmcnt(" #N ")" ::: "memory"); \
                       __builtin_amdgcn_sched_barrier(0); } while (0)

// ---------------------------------------------------------------------------
// GLOBAL K-ORDER (both GEMMs): r = t*256 + c  (tap-major).
//
// XCD-AWARE BLOCK SWIZZLE (both hot kernels): dispatch round-robins blocks
// across the 8 XCDs (xcd = bid % 8). We map each XCD's resident blocks onto
// one 32-row band of ONE image, so the per-XCD L2 working set is
//   wregb/A (1.18/0.29 MB) + x row-band (~2.2 MB) + offf band (~0.2 MB) < 4 MB
// -> A-matrix and x-band are fetched from L3 once per XCD, not once per block.
// ---------------------------------------------------------------------------

// Kernel 0a: offset/mask conv weights -> hi/lo bf16 A[32][2304], r = t*256+c
__global__ void kprep(const float* __restrict__ woff, const float* __restrict__ wmod,
                      u16* __restrict__ ah, u16* __restrict__ al) {
    int i = blockIdx.x * 256 + threadIdx.x;      // 288 blocks -> 73728 exact
    if (i >= 32 * 2304) return;
    int oc = i / 2304, r = i - oc * 2304;
    int t = r >> 8, c = r & 255;
    float v = 0.f;
    if (oc < 18)      v = woff[oc * 2304 + c * 9 + t];
    else if (oc < 27) v = wmod[(oc - 18) * 2304 + c * 9 + t];
    u32 hb = f2bf(v);
    u32 lb = f2bf(v - bf2f((u16)hb));
    ah[i] = (u16)hb;
    al[i] = (u16)lb;
}

// Kernel 0b: w_reg f32 -> bf16, layout [o][t*256+c] (matches gather K-order).
__global__ void kwreg(const float* __restrict__ wreg, u16* __restrict__ wregb) {
    int i = blockIdx.x * 256 + threadIdx.x;      // 2304 blocks exact
    int o = i / 2304, r = i - o * 2304;
    int t = r >> 8, c = r & 255;
    wregb[i] = (u16)f2bf(wreg[o * 2304 + c * 9 + t]);
}

// ---------------------------------------------------------------------------
// Kernel 1: offset/mask conv as MFMA GEMM, M=32 (27 live), N=16384, K=2304.
// hi/lo bf16 split on both operands -> 3 MFMAs, fp32-equivalent precision.
// Pipelined (asm loads in flight over MFMA), one barrier per kt.
// Block swizzle: xcd -> (image, 32-row band), j -> (row-in-band, half-row).
// ---------------------------------------------------------------------------
__global__ __launch_bounds__(256) void koffg(const float* __restrict__ x,
                                             const u16* __restrict__ ah_g,
                                             const u16* __restrict__ al_g,
                                             const float* __restrict__ boff,
                                             const float* __restrict__ bmod,
                                             float* __restrict__ offf) {
    __shared__ u16 Ah[2][32 * 72], Al[2][32 * 72]; // 32 oc-rows, 64 k + 8 pad
    __shared__ u16 Bh[2][32 * 72], Bl[2][32 * 72]; // 32 n-rows,  64 k + 8 pad
    int tid = threadIdx.x;
    // XCD swizzle: 512 blocks, xcd = bid&7 -> (img, band), j -> row/half
    int bid = blockIdx.x;
    int xcd = bid & 7, j = bid >> 3;             // j in [0,64)
    int img = xcd >> 1;
    int row = ((xcd & 1) << 5) + (j >> 1);
    int n0 = ((img << 6) + row) * 64 + (j & 1) * 32;
    int b = n0 >> 12, h0 = (n0 & 4095) >> 6, w0 = n0 & 63;
    int lane = tid & 63, wv = tid >> 6;
    int mt = wv & 1, nt = wv >> 1;               // 2 m-tiles x 2 n-tiles of 16
    int col = lane & 15, quad = lane >> 4;

    int aoc = tid >> 3, ak0 = (tid & 7) * 8;     // A staging role
    int nl = tid & 31, cl0 = (tid >> 5) * 8;     // B staging role

    const float* xb = x + ((long)b << 20);       // image base (SGPR)
    u32 avoff0 = (u32)(aoc * 2304 + ak0) * 2;    // bytes into ah_g/al_g

    f32x4 acc = (f32x4){0.f, 0.f, 0.f, 0.f};

    uint4 pah, pal;
    float xv[8];
    bool  vm;

    auto issue = [&](int kt) {                   // 10 asm loads, stay in flight
        int t = kt >> 2, c0 = (kt & 3) << 6, r0 = kt * 64;
        int dy = t / 3 - 1, dx = t % 3 - 1;
        pah = gload4(ah_g, avoff0 + (u32)r0 * 2);
        pal = gload4(al_g, avoff0 + (u32)r0 * 2);
        int hp = h0 + dy, wp = w0 + nl + dx;
        vm = ((unsigned)hp < 64u) && ((unsigned)wp < 64u);
        int hc = min(max(hp, 0), 63), wc = min(max(wp, 0), 63);
        u32 pix4 = (u32)(hc * 64 + wc) * 4;
#pragma unroll
        for (int i = 0; i < 8; i++)
            xv[i] = gload(xb, ((u32)(c0 + cl0 + i) << 14) + pix4);
    };
    auto stores = [&](int buf) {                 // after WAITVM(0)
        u32 whi[4], wlo[4];
#pragma unroll
        for (int i = 0; i < 8; i++) {
            float v = vm ? xv[i] : 0.f;
            u32 hb = f2bf(v);
            u32 lb = f2bf(v - bf2f((u16)hb));
            if (i & 1) { whi[i >> 1] |= hb << 16; wlo[i >> 1] |= lb << 16; }
            else       { whi[i >> 1]  = hb;       wlo[i >> 1]  = lb; }
        }
        *(uint4*)&Ah[buf][aoc * 72 + ak0] = pah;
        *(uint4*)&Al[buf][aoc * 72 + ak0] = pal;
        *(uint4*)&Bh[buf][nl * 72 + cl0] = make_uint4(whi[0], whi[1], whi[2], whi[3]);
        *(uint4*)&Bl[buf][nl * 72 + cl0] = make_uint4(wlo[0], wlo[1], wlo[2], wlo[3]);
    };

    issue(0);
    WAITVM(0);
    stores(0);
    __syncthreads();

    for (int kt = 0; kt < 36; kt++) {
        int cur = kt & 1, nxt = kt + 1;
        if (nxt < 36) issue(nxt);                // in flight over MFMA phase
#pragma unroll
        for (int ks = 0; ks < 2; ks++) {
            int ko = ks * 32 + quad * 8;
            bf16x8 fah = *(const bf16x8*)&Ah[cur][(mt * 16 + col) * 72 + ko];
            bf16x8 fal = *(const bf16x8*)&Al[cur][(mt * 16 + col) * 72 + ko];
            bf16x8 fbh = *(const bf16x8*)&Bh[cur][(nt * 16 + col) * 72 + ko];
            bf16x8 fbl = *(const bf16x8*)&Bl[cur][(nt * 16 + col) * 72 + ko];
            acc = __builtin_amdgcn_mfma_f32_16x16x32_bf16(fah, fbh, acc, 0, 0, 0);
            acc = __builtin_amdgcn_mfma_f32_16x16x32_bf16(fah, fbl, acc, 0, 0, 0);
            acc = __builtin_amdgcn_mfma_f32_16x16x32_bf16(fal, fbh, acc, 0, 0, 0);
        }
        if (nxt < 36) {
            WAITVM(0);                           // gathers done; latency hidden
            stores(nxt & 1);
        }
        __syncthreads();                         // one barrier per kt
    }

    int n = n0 + nt * 16 + col;
#pragma unroll
    for (int r = 0; r < 4; r++) {
        int oc = mt * 16 + quad * 4 + r;
        float s = acc[r];
        if (oc < 18) {
            int ch = 3 * (oc >> 1) + (oc & 1);   // even oc -> dy, odd -> dx
            offf[(ch << 14) + n] = s + boff[oc];
        } else if (oc < 27) {
            float tt = s + bmod[oc - 18];
            int ch = 3 * (oc - 18) + 2;
            offf[(ch << 14) + n] = 2.f / (1.f + __expf(-tt));
        }
    }
}

// ---------------------------------------------------------------------------
// Kernel 2 (FUSED, PIPELINED, XCD-SWIZZLED): sampling + GEMM + BN + ReLU.
// Block = 64 pixels (one row) x 256 outputs, 512 thr, 8 waves, grid 256.
// Swizzle: xcd = bid&7 -> (image = xcd>>1, band = xcd&1); row = band*32 + bid>>3.
// Per-XCD L2 set: wregb 1.18 MB + x band 2.2 MB + offf band 0.2 MB < 4 MB.
// Per kt: issue 32 asm gathers(kt+1) + 4 A-DMAs(kt+1) -> MFMA(kt) ->
// vmcnt(4) -> weight/pack/ds_write -> ONE barrier.
// ---------------------------------------------------------------------------
__global__ __launch_bounds__(512, 2) void kfused(const float* __restrict__ x,
                                                 const float* __restrict__ offf,
                                                 const u16* __restrict__ wregb,
                                                 const float* __restrict__ gamma,
                                                 const float* __restrict__ beta,
                                                 const float* __restrict__ rmean,
                                                 const float* __restrict__ rvar,
                                                 float* __restrict__ out) {
    __shared__ u16 Wl[2][256 * 64];  // [buf][o][k] granule-XOR-swizzled, 64 KB
    __shared__ u16 Sl[2][8 * 64 * 8];// [buf][c-octet][n][8ch], 16 KB
    int tid = threadIdx.x;
    int lane = tid & 63, wv = tid >> 6;
    int nl = lane, og = wv;                      // pixel-in-block, channel octet
    // XCD swizzle: 256 blocks -> xcd gets a 32-row band of one image
    int bid = blockIdx.x;
    int xcd = bid & 7;
    int bb  = xcd >> 1;                          // image   (block-uniform)
    int h   = ((xcd & 1) << 5) + (bid >> 3);     // row     (block-uniform)
    int nbase = ((bb << 6) + h) * 64;            // first pixel of this row
    int n  = nbase + nl;                         // global pixel id
    int wo = (wv >> 1) * 64, wn = (wv & 1) * 32; // wave output tile 64o x 32n
    int col = lane & 15, quad = lane >> 4;

    const float* xb = x + ((long)bb << 20);      // image base (SGPR)

    f32x4 acc[4][2];
#pragma unroll
    for (int i = 0; i < 4; i++)
#pragma unroll
        for (int j = 0; j < 2; j++) acc[i][j] = (f32x4){0.f, 0.f, 0.f, 0.f};

    u32   v00 = 0, v01 = 0, v10 = 0, v11 = 0;    // neighbor byte offsets
    float s00 = 0.f, s01 = 0.f, s10 = 0.f, s11 = 0.f;
    float g00[8], g01[8], g10[8], g11[8];        // in-flight gather values

    auto tapst = [&](int t) {                    // rebuild tap state (every 4 kt)
        int g = t / 3, tx = t - 3 * g;
        float dy = offf[((3 * t + 0) << 14) + n];
        float dx = offf[((3 * t + 1) << 14) + n];
        float m  = offf[((3 * t + 2) << 14) + n];
        float py = (float)(h - 1 + g) + dy;
        float px = (float)(nl - 1 + tx) + dx;
        float y0f = floorf(py), x0f = floorf(px);
        float wy = py - y0f, wx = px - x0f;
        int iy0 = (int)y0f, ix0 = (int)x0f;
        int iy1 = iy0 + 1, ix1 = ix0 + 1;
        bool vy0 = (unsigned)iy0 < 64u, vy1 = (unsigned)iy1 < 64u;
        bool vx0 = (unsigned)ix0 < 64u, vx1 = (unsigned)ix1 < 64u;
        int cy0 = min(max(iy0, 0), 63), cy1 = min(max(iy1, 0), 63);
        int cx0 = min(max(ix0, 0), 63), cx1 = min(max(ix1, 0), 63);
        v00 = (u32)(cy0 * 64 + cx0) * 4; v01 = (u32)(cy0 * 64 + cx1) * 4;
        v10 = (u32)(cy1 * 64 + cx0) * 4; v11 = (u32)(cy1 * 64 + cx1) * 4;
        float a = 1.f - wy, bw = 1.f - wx;
        s00 = (vy0 && vx0) ? a  * bw * m : 0.f;
        s01 = (vy0 && vx1) ? a  * wx * m : 0.f;
        s10 = (vy1 && vx0) ? wy * bw * m : 0.f;
        s11 = (vy1 && vx1) ? wy * wx * m : 0.f;
    };
    auto gissue = [&](int kt) {                  // 32 asm gathers, in flight
        u32 cb = (u32)(og * 8 + ((kt & 3) << 6)) << 14;  // channel byte base
#pragma unroll
        for (int cc = 0; cc < 8; cc++) {
            u32 co = cb + ((u32)cc << 14);
            g00[cc] = gload(xb, co + v00);
            g01[cc] = gload(xb, co + v01);
            g10[cc] = gload(xb, co + v10);
            g11[cc] = gload(xb, co + v11);
        }
    };
    auto dmaA = [&](int kt, int buf) {           // async A staging, 32 KB
#pragma unroll
        for (int i = 0; i < 4; i++) {
            int cidx = tid + i * 512;
            int o = cidx >> 3, qp = cidx & 7;
            int ql = qp ^ (o & 7);               // source-side XOR swizzle
            load_lds16(wregb + (long)o * 2304 + kt * 64 + ql * 8,
                       &Wl[buf][cidx * 8]);
        }
    };
    auto bwrite = [&](int buf) {                 // after WAITVM: weight+pack+write
        u32 wd[4];
#pragma unroll
        for (int cc = 0; cc < 8; cc++) {
            float v = s00 * g00[cc] + s01 * g01[cc] +
                      s10 * g10[cc] + s11 * g11[cc];
            u32 bv = f2bf(v);
            if (cc & 1) wd[cc >> 1] |= bv << 16;
            else        wd[cc >> 1]  = bv;
        }
        *(uint4*)&Sl[buf][(og * 64 + nl) * 8] =
            make_uint4(wd[0], wd[1], wd[2], wd[3]);
    };

    // prologue: fill buffer 0
    tapst(0);
    gissue(0);
    dmaA(0, 0);
    WAITVM(0);
    bwrite(0);
    __syncthreads();

    for (int kt = 0; kt < 36; kt++) {
        int cur = kt & 1, nxt = kt + 1;
        if (nxt < 36) {
            if ((nxt & 3) == 0) tapst(nxt >> 2);
            gissue(nxt);                         // 32 oldest outstanding vmem
            dmaA(nxt, nxt & 1);                  // 4 newest (drain at barrier)
        }
#pragma unroll
        for (int ks = 0; ks < 2; ks++) {
            bf16x8 af[4], bfr[2];
#pragma unroll
            for (int i = 0; i < 4; i++) {
                int r = wo + i * 16 + col;
                int ph = (ks * 4 + quad) ^ (r & 7);
                af[i] = *(const bf16x8*)&Wl[cur][r * 64 + ph * 8];
            }
#pragma unroll
            for (int j = 0; j < 2; j++)
                bfr[j] = *(const bf16x8*)&Sl[cur][((ks * 4 + quad) * 64 +
                                                   (wn + j * 16 + col)) * 8];
#pragma unroll
            for (int i = 0; i < 4; i++)
#pragma unroll
                for (int j = 0; j < 2; j++)
                    acc[i][j] = __builtin_amdgcn_mfma_f32_16x16x32_bf16(
                        af[i], bfr[j], acc[i][j], 0, 0, 0);
        }
        if (nxt < 36) {
            WAITVM(4);                           // gathers done, DMA may fly
            bwrite(nxt & 1);
        }
        __syncthreads();                         // drains DMA + ds_write; one/kt
    }

    // epilogue: BN + ReLU, D layout: row(o) = quad*4+reg, col(n) = lane&15
#pragma unroll
    for (int i = 0; i < 4; i++) {
        int ob = wo + i * 16 + quad * 4;
        float inv[4], add[4];
#pragma unroll
        for (int r = 0; r < 4; r++) {
            int o = ob + r;
            float iv = gamma[o] * rsqrtf(rvar[o] + 1e-5f);
            inv[r] = iv; add[r] = beta[o] - rmean[o] * iv;
        }
#pragma unroll
        for (int j = 0; j < 2; j++) {
            int n_g = nbase + wn + j * 16 + col;
            int bq = n_g >> 12, hw = n_g & 4095;
            float* op = out + ((long)bq << 20) + hw;
#pragma unroll
            for (int r = 0; r < 4; r++) {
                float v = acc[i][j][r] * inv[r] + add[r];
                v = fmaxf(v, 0.f);
                op[(long)(ob + r) << 12] = v;
            }
        }
    }
}

// ---------------------------------------------------------------------------
extern "C" void kernel_launch(void* const* d_in, const int* in_sizes, int n_in,
                              void* d_out, int out_size, void* d_ws, size_t ws_size,
                              hipStream_t stream) {
    const float* x     = (const float*)d_in[0];
    const float* woff  = (const float*)d_in[1];
    const float* boff  = (const float*)d_in[2];
    const float* wmod  = (const float*)d_in[3];
    const float* bmod  = (const float*)d_in[4];
    const float* wreg  = (const float*)d_in[5];
    const float* gamma = (const float*)d_in[6];
    const float* beta  = (const float*)d_in[7];
    const float* rmean = (const float*)d_in[8];
    const float* rvar  = (const float*)d_in[9];
    float* out = (float*)d_out;

    char* ws = (char*)d_ws;
    // ws map:
    //   [0x000000, 0x024000) wph   bf16  144 KB (A hi, koffg)
    //   [0x040000, 0x064000) wpl   bf16  144 KB (A lo)
    //   [0x080000, 0x23C000) offf  fp32  1.77 MB
    //   [0x240000, 0x360000) wregb bf16  1.18 MB ([o][t*256+c] order)
    u16*   wph   = (u16*)(ws);
    u16*   wpl   = (u16*)(ws + 0x40000u);
    float* offf  = (float*)(ws + 0x80000u);
    u16*   wregb = (u16*)(ws + 0x240000u);

    kprep<<<288,  256, 0, stream>>>(woff, wmod, wph, wpl);
    kwreg<<<2304, 256, 0, stream>>>(wreg, wregb);
    koffg<<<512,  256, 0, stream>>>(x, wph, wpl, boff, bmod, offf);
    kfused<<<256, 512, 0, stream>>>(x, offf, wregb, gamma, beta,
                                    rmean, rvar, out);
}

// Round 8
// 223.865 us; speedup vs baseline: 1.1100x; 1.0818x over previous
//
#include <hip/hip_runtime.h>
#include <hip/hip_bf16.h>

typedef unsigned short u16;
typedef unsigned int   u32;
typedef short   bf16x8 __attribute__((ext_vector_type(8)));  // bf16 carried as i16
typedef float   f32x4  __attribute__((ext_vector_type(4)));

__device__ __forceinline__ float bf2f(u16 u) {
    u32 t = ((u32)u) << 16;
    return __builtin_bit_cast(float, t);
}
__device__ __forceinline__ u32 f2bf(float f) {
    u32 u = __builtin_bit_cast(u32, f);
    return (u + 0x7FFFu + ((u >> 16) & 1u)) >> 16;   // RNE
}
// async global->LDS DMA, 16 B per lane (dst = wave-uniform base + lane*16)
__device__ __forceinline__ void load_lds16(const u16* g, u16* l) {
    __builtin_amdgcn_global_load_lds(
        (const __attribute__((address_space(1))) u32*)(const void*)g,
        (__attribute__((address_space(3))) u32*)(void*)l, 16, 0, 0);
}
// Inline-asm loads (saddr form): compiler cannot sink these or auto-wait on
// them -> true async issue, paired with manual vmcnt (rule #18).
// ALL loads 16B-aligned dwordx4 (no alignment hazards).
__device__ __forceinline__ uint4 gload4(const u16* sbase, u32 voff) {
    uint4 r;
    asm volatile("global_load_dwordx4 %0, %1, %2"
                 : "=v"(r) : "v"(voff), "s"(sbase) : "memory");
    return r;
}
__device__ __forceinline__ f32x4 gload4f(const float* sbase, u32 voff) {
    f32x4 r;
    asm volatile("global_load_dwordx4 %0, %1, %2"
                 : "=v"(r) : "v"(voff), "s"(sbase) : "memory");
    return r;
}
#define WAITVM(N) do { asm volatile("s_waitcnt vmcnt(" #N ")" ::: "memory"); \
                       __builtin_amdgcn_sched_barrier(0); } while (0)

// ---------------------------------------------------------------------------
// GLOBAL K-ORDER (both GEMMs): r = t*256 + c  (tap-major).
// XCD swizzle (verified r6: FETCH 289->14.6 MB): xcd = bid&7 -> row band.
// NEW: channel-last transpose xt[b][pixel][c] so every 8-channel octet is 32
// contiguous, 32B-aligned bytes -> one dwordx4 pair per pixel touch. Cuts
// wave-vmem instrs 3x (kfused 288->96 /CU-kt, koffg 80->32), testing the
// ~26 cyc/vmem-instr service-rate model (r0/r6 fits; latency+BW falsified).
// ---------------------------------------------------------------------------

// Kernel 0a: offset/mask conv weights -> hi/lo bf16 A[32][2304], r = t*256+c
__global__ void kprep(const float* __restrict__ woff, const float* __restrict__ wmod,
                      u16* __restrict__ ah, u16* __restrict__ al) {
    int i = blockIdx.x * 256 + threadIdx.x;      // 288 blocks -> 73728 exact
    if (i >= 32 * 2304) return;
    int oc = i / 2304, r = i - oc * 2304;
    int t = r >> 8, c = r & 255;
    float v = 0.f;
    if (oc < 18)      v = woff[oc * 2304 + c * 9 + t];
    else if (oc < 27) v = wmod[(oc - 18) * 2304 + c * 9 + t];
    u32 hb = f2bf(v);
    u32 lb = f2bf(v - bf2f((u16)hb));
    ah[i] = (u16)hb;
    al[i] = (u16)lb;
}

// Kernel 0b: w_reg f32 -> bf16, layout [o][t*256+c] (matches gather K-order).
__global__ void kwreg(const float* __restrict__ wreg, u16* __restrict__ wregb) {
    int i = blockIdx.x * 256 + threadIdx.x;      // 2304 blocks exact
    int o = i / 2304, r = i - o * 2304;
    int t = r >> 8, c = r & 255;
    wregb[i] = (u16)f2bf(wreg[o * 2304 + c * 9 + t]);
}

// Kernel 0c: transpose x[b][c][p] -> xt[b][p][c]  (channel-last, 16 MB).
// 64ch x 64px LDS tile; both global accesses fully coalesced.
__global__ __launch_bounds__(256) void ktrans(const float* __restrict__ x,
                                              float* __restrict__ xt) {
    __shared__ float T[64][65];
    int t = threadIdx.x;
    int pl = t & 63, cr = t >> 6;                // 4 rows per pass
    int p0 = blockIdx.x * 64;                    // pixel tile
    int c0 = blockIdx.y * 64;                    // channel tile
    int b  = blockIdx.z;
    const float* xb  = x  + ((long)b << 20);
    float*       xtb = xt + ((long)b << 20);
#pragma unroll
    for (int i = 0; i < 16; i++) {
        int c = cr + i * 4;
        T[c][pl] = xb[((long)(c0 + c) << 12) + p0 + pl];
    }
    __syncthreads();
#pragma unroll
    for (int i = 0; i < 16; i++) {
        int p = cr + i * 4;
        xtb[(long)(p0 + p) * 256 + c0 + pl] = T[pl][p];
    }
}

// ---------------------------------------------------------------------------
// Kernel 1: offset/mask conv as MFMA GEMM, M=32 (27 live), N=16384, K=2304.
// r6-proven 1-deep pipeline; B-operand now 2x dwordx4 from xt (4 vmem
// instrs/wave-kt, was 10). One barrier per kt.
// ---------------------------------------------------------------------------
__global__ __launch_bounds__(256) void koffg(const float* __restrict__ xt,
                                             const u16* __restrict__ ah_g,
                                             const u16* __restrict__ al_g,
                                             const float* __restrict__ boff,
                                             const float* __restrict__ bmod,
                                             float* __restrict__ offf) {
    __shared__ u16 Ah[2][32 * 72], Al[2][32 * 72]; // 32 oc-rows, 64 k + 8 pad
    __shared__ u16 Bh[2][32 * 72], Bl[2][32 * 72]; // 32 n-rows,  64 k + 8 pad
    int tid = threadIdx.x;
    // XCD swizzle: 512 blocks, xcd = bid&7 -> (img, band), j -> row/half
    int bid = blockIdx.x;
    int xcd = bid & 7, j = bid >> 3;             // j in [0,64)
    int img = xcd >> 1;
    int row = ((xcd & 1) << 5) + (j >> 1);
    int n0 = ((img << 6) + row) * 64 + (j & 1) * 32;
    int b = n0 >> 12, h0 = (n0 & 4095) >> 6, w0 = n0 & 63;
    int lane = tid & 63, wv = tid >> 6;
    int mt = wv & 1, nt = wv >> 1;               // 2 m-tiles x 2 n-tiles of 16
    int col = lane & 15, quad = lane >> 4;

    int aoc = tid >> 3, ak0 = (tid & 7) * 8;     // A staging role
    int nl = tid & 31, cl0 = (tid >> 5) * 8;     // B staging role

    const float* xtb = xt + ((long)b << 20);     // image base (SGPR)
    u32 avoff0 = (u32)(aoc * 2304 + ak0) * 2;    // bytes into ah_g/al_g

    f32x4 acc = (f32x4){0.f, 0.f, 0.f, 0.f};

    uint4 pah, pal;
    f32x4 xw0, xw1;
    bool  vm;

    auto issue = [&](int kt) {                   // 4 asm loads, stay in flight
        int t = kt >> 2, c0 = (kt & 3) << 6, r0 = kt * 64;
        int dy = t / 3 - 1, dx = t % 3 - 1;
        pah = gload4(ah_g, avoff0 + (u32)r0 * 2);
        pal = gload4(al_g, avoff0 + (u32)r0 * 2);
        int hp = h0 + dy, wp = w0 + nl + dx;
        vm = ((unsigned)hp < 64u) && ((unsigned)wp < 64u);
        int hc = min(max(hp, 0), 63), wc = min(max(wp, 0), 63);
        u32 pixb = (u32)(hc * 64 + wc) << 10;    // pixel record (1 KB)
        u32 cb   = (u32)(c0 + cl0) << 2;         // channel byte offset (32B-al)
        xw0 = gload4f(xtb, pixb + cb);           // ch c..c+3
        xw1 = gload4f(xtb, pixb + cb + 16);      // ch c+4..c+7
    };
    auto stores = [&](int buf) {                 // after WAITVM(0)
        u32 whi[4], wlo[4];
#pragma unroll
        for (int i = 0; i < 8; i++) {
            float xvi = (i < 4) ? xw0[i] : xw1[i - 4];
            float v = vm ? xvi : 0.f;
            u32 hb = f2bf(v);
            u32 lb = f2bf(v - bf2f((u16)hb));
            if (i & 1) { whi[i >> 1] |= hb << 16; wlo[i >> 1] |= lb << 16; }
            else       { whi[i >> 1]  = hb;       wlo[i >> 1]  = lb; }
        }
        *(uint4*)&Ah[buf][aoc * 72 + ak0] = pah;
        *(uint4*)&Al[buf][aoc * 72 + ak0] = pal;
        *(uint4*)&Bh[buf][nl * 72 + cl0] = make_uint4(whi[0], whi[1], whi[2], whi[3]);
        *(uint4*)&Bl[buf][nl * 72 + cl0] = make_uint4(wlo[0], wlo[1], wlo[2], wlo[3]);
    };

    issue(0);
    WAITVM(0);
    stores(0);
    __syncthreads();

    for (int kt = 0; kt < 36; kt++) {
        int cur = kt & 1, nxt = kt + 1;
        if (nxt < 36) issue(nxt);                // in flight over MFMA phase
#pragma unroll
        for (int ks = 0; ks < 2; ks++) {
            int ko = ks * 32 + quad * 8;
            bf16x8 fah = *(const bf16x8*)&Ah[cur][(mt * 16 + col) * 72 + ko];
            bf16x8 fal = *(const bf16x8*)&Al[cur][(mt * 16 + col) * 72 + ko];
            bf16x8 fbh = *(const bf16x8*)&Bh[cur][(nt * 16 + col) * 72 + ko];
            bf16x8 fbl = *(const bf16x8*)&Bl[cur][(nt * 16 + col) * 72 + ko];
            acc = __builtin_amdgcn_mfma_f32_16x16x32_bf16(fah, fbh, acc, 0, 0, 0);
            acc = __builtin_amdgcn_mfma_f32_16x16x32_bf16(fah, fbl, acc, 0, 0, 0);
            acc = __builtin_amdgcn_mfma_f32_16x16x32_bf16(fal, fbh, acc, 0, 0, 0);
        }
        if (nxt < 36) {
            WAITVM(0);                           // loads done; latency hidden
            stores(nxt & 1);
        }
        __syncthreads();                         // one barrier per kt
    }

    int n = n0 + nt * 16 + col;
#pragma unroll
    for (int r = 0; r < 4; r++) {
        int oc = mt * 16 + quad * 4 + r;
        float s = acc[r];
        if (oc < 18) {
            int ch = 3 * (oc >> 1) + (oc & 1);   // even oc -> dy, odd -> dx
            offf[(ch << 14) + n] = s + boff[oc];
        } else if (oc < 27) {
            float tt = s + bmod[oc - 18];
            int ch = 3 * (oc - 18) + 2;
            offf[(ch << 14) + n] = 2.f / (1.f + __expf(-tt));
        }
    }
}

// ---------------------------------------------------------------------------
// Kernel 2 (FUSED): sampling + GEMM + BN + ReLU. Gathers now channel-last:
// per neighbor pixel, 8 channels = 2x 16B-aligned dwordx4 -> 8 gather
// instrs/thread-kt (was 32). Same values, weights, accumulation order.
// Per kt: issue 8 gathers(kt+1) + 4 A-DMAs(kt+1) -> MFMA(kt) -> vmcnt(4)
// -> weight/pack/ds_write -> ONE barrier. XCD row-band swizzle kept.
// ---------------------------------------------------------------------------
__global__ __launch_bounds__(512, 2) void kfused(const float* __restrict__ xt,
                                                 const float* __restrict__ offf,
                                                 const u16* __restrict__ wregb,
                                                 const float* __restrict__ gamma,
                                                 const float* __restrict__ beta,
                                                 const float* __restrict__ rmean,
                                                 const float* __restrict__ rvar,
                                                 float* __restrict__ out) {
    __shared__ u16 Wl[2][256 * 64];  // [buf][o][k] granule-XOR-swizzled, 64 KB
    __shared__ u16 Sl[2][8 * 64 * 8];// [buf][c-octet][n][8ch], 16 KB
    int tid = threadIdx.x;
    int lane = tid & 63, wv = tid >> 6;
    int nl = lane, og = wv;                      // pixel-in-block, channel octet
    // XCD swizzle: 256 blocks -> xcd gets a 32-row band of one image
    int bid = blockIdx.x;
    int xcd = bid & 7;
    int bb  = xcd >> 1;                          // image   (block-uniform)
    int h   = ((xcd & 1) << 5) + (bid >> 3);     // row     (block-uniform)
    int nbase = ((bb << 6) + h) * 64;            // first pixel of this row
    int n  = nbase + nl;                         // global pixel id
    int wo = (wv >> 1) * 64, wn = (wv & 1) * 32; // wave output tile 64o x 32n
    int col = lane & 15, quad = lane >> 4;

    const float* xb = xt + ((long)bb << 20);     // image base (SGPR)

    f32x4 acc[4][2];
#pragma unroll
    for (int i = 0; i < 4; i++)
#pragma unroll
        for (int j = 0; j < 2; j++) acc[i][j] = (f32x4){0.f, 0.f, 0.f, 0.f};

    u32   p00 = 0, p01 = 0, p10 = 0, p11 = 0;    // neighbor pixel byte offsets
    float s00 = 0.f, s01 = 0.f, s10 = 0.f, s11 = 0.f;
    f32x4 ga0, ga1, gb0, gb1, gc0, gc1, gd0, gd1; // in-flight gather octets

    auto tapst = [&](int t) {                    // rebuild tap state (every 4 kt)
        int g = t / 3, tx = t - 3 * g;
        float dy = offf[((3 * t + 0) << 14) + n];
        float dx = offf[((3 * t + 1) << 14) + n];
        float m  = offf[((3 * t + 2) << 14) + n];
        float py = (float)(h - 1 + g) + dy;
        float px = (float)(nl - 1 + tx) + dx;
        float y0f = floorf(py), x0f = floorf(px);
        float wy = py - y0f, wx = px - x0f;
        int iy0 = (int)y0f, ix0 = (int)x0f;
        int iy1 = iy0 + 1, ix1 = ix0 + 1;
        bool vy0 = (unsigned)iy0 < 64u, vy1 = (unsigned)iy1 < 64u;
        bool vx0 = (unsigned)ix0 < 64u, vx1 = (unsigned)ix1 < 64u;
        int cy0 = min(max(iy0, 0), 63), cy1 = min(max(iy1, 0), 63);
        int cx0 = min(max(ix0, 0), 63), cx1 = min(max(ix1, 0), 63);
        p00 = (u32)(cy0 * 64 + cx0) << 10; p01 = (u32)(cy0 * 64 + cx1) << 10;
        p10 = (u32)(cy1 * 64 + cx0) << 10; p11 = (u32)(cy1 * 64 + cx1) << 10;
        float a = 1.f - wy, bw = 1.f - wx;
        s00 = (vy0 && vx0) ? a  * bw * m : 0.f;
        s01 = (vy0 && vx1) ? a  * wx * m : 0.f;
        s10 = (vy1 && vx0) ? wy * bw * m : 0.f;
        s11 = (vy1 && vx1) ? wy * wx * m : 0.f;
    };
    auto gissue = [&](int kt) {                  // 8 asm dwordx4 gathers
        u32 co = (u32)(og * 8 + ((kt & 3) << 6)) << 2;   // channel byte offset
        ga0 = gload4f(xb, p00 + co); ga1 = gload4f(xb, p00 + co + 16);
        gb0 = gload4f(xb, p01 + co); gb1 = gload4f(xb, p01 + co + 16);
        gc0 = gload4f(xb, p10 + co); gc1 = gload4f(xb, p10 + co + 16);
        gd0 = gload4f(xb, p11 + co); gd1 = gload4f(xb, p11 + co + 16);
    };
    auto dmaA = [&](int kt, int buf) {           // async A staging, 32 KB
#pragma unroll
        for (int i = 0; i < 4; i++) {
            int cidx = tid + i * 512;
            int o = cidx >> 3, qp = cidx & 7;
            int ql = qp ^ (o & 7);               // source-side XOR swizzle
            load_lds16(wregb + (long)o * 2304 + kt * 64 + ql * 8,
                       &Wl[buf][cidx * 8]);
        }
    };
    auto bwrite = [&](int buf) {                 // after WAITVM: weight+pack+write
        u32 wd[4];
#pragma unroll
        for (int cc = 0; cc < 8; cc++) {
            float va = (cc < 4) ? ga0[cc] : ga1[cc - 4];   // x[cy0][cx0][c]
            float vb = (cc < 4) ? gb0[cc] : gb1[cc - 4];   // x[cy0][cx1][c]
            float vc = (cc < 4) ? gc0[cc] : gc1[cc - 4];   // x[cy1][cx0][c]
            float vd = (cc < 4) ? gd0[cc] : gd1[cc - 4];   // x[cy1][cx1][c]
            float v = s00 * va + s01 * vb + s10 * vc + s11 * vd;
            u32 bv = f2bf(v);
            if (cc & 1) wd[cc >> 1] |= bv << 16;
            else        wd[cc >> 1]  = bv;
        }
        *(uint4*)&Sl[buf][(og * 64 + nl) * 8] =
            make_uint4(wd[0], wd[1], wd[2], wd[3]);
    };

    // prologue: fill buffer 0
    tapst(0);
    gissue(0);
    dmaA(0, 0);
    WAITVM(0);
    bwrite(0);
    __syncthreads();

    for (int kt = 0; kt < 36; kt++) {
        int cur = kt & 1, nxt = kt + 1;
        if (nxt < 36) {
            if ((nxt & 3) == 0) tapst(nxt >> 2);
            gissue(nxt);                         // 8 oldest outstanding vmem
            dmaA(nxt, nxt & 1);                  // 4 newest (drain at barrier)
        }
#pragma unroll
        for (int ks = 0; ks < 2; ks++) {
            bf16x8 af[4], bfr[2];
#pragma unroll
            for (int i = 0; i < 4; i++) {
                int r = wo + i * 16 + col;
                int ph = (ks * 4 + quad) ^ (r & 7);
                af[i] = *(const bf16x8*)&Wl[cur][r * 64 + ph * 8];
            }
#pragma unroll
            for (int j = 0; j < 2; j++)
                bfr[j] = *(const bf16x8*)&Sl[cur][((ks * 4 + quad) * 64 +
                                                   (wn + j * 16 + col)) * 8];
#pragma unroll
            for (int i = 0; i < 4; i++)
#pragma unroll
                for (int j = 0; j < 2; j++)
                    acc[i][j] = __builtin_amdgcn_mfma_f32_16x16x32_bf16(
                        af[i], bfr[j], acc[i][j], 0, 0, 0);
        }
        if (nxt < 36) {
            WAITVM(4);                           // gathers done, DMA may fly
            bwrite(nxt & 1);
        }
        __syncthreads();                         // drains DMA + ds_write; one/kt
    }

    // epilogue: BN + ReLU, D layout: row(o) = quad*4+reg, col(n) = lane&15
#pragma unroll
    for (int i = 0; i < 4; i++) {
        int ob = wo + i * 16 + quad * 4;
        float inv[4], add[4];
#pragma unroll
        for (int r = 0; r < 4; r++) {
            int o = ob + r;
            float iv = gamma[o] * rsqrtf(rvar[o] + 1e-5f);
            inv[r] = iv; add[r] = beta[o] - rmean[o] * iv;
        }
#pragma unroll
        for (int j = 0; j < 2; j++) {
            int n_g = nbase + wn + j * 16 + col;
            int bq = n_g >> 12, hw = n_g & 4095;
            float* op = out + ((long)bq << 20) + hw;
#pragma unroll
            for (int r = 0; r < 4; r++) {
                float v = acc[i][j][r] * inv[r] + add[r];
                v = fmaxf(v, 0.f);
                op[(long)(ob + r) << 12] = v;
            }
        }
    }
}

// ---------------------------------------------------------------------------
extern "C" void kernel_launch(void* const* d_in, const int* in_sizes, int n_in,
                              void* d_out, int out_size, void* d_ws, size_t ws_size,
                              hipStream_t stream) {
    const float* x     = (const float*)d_in[0];
    const float* woff  = (const float*)d_in[1];
    const float* boff  = (const float*)d_in[2];
    const float* wmod  = (const float*)d_in[3];
    const float* bmod  = (const float*)d_in[4];
    const float* wreg  = (const float*)d_in[5];
    const float* gamma = (const float*)d_in[6];
    const float* beta  = (const float*)d_in[7];
    const float* rmean = (const float*)d_in[8];
    const float* rvar  = (const float*)d_in[9];
    float* out = (float*)d_out;

    char* ws = (char*)d_ws;
    // ws map:
    //   [0x000000, 0x024000)  wph   bf16  144 KB (A hi, koffg)
    //   [0x040000, 0x064000)  wpl   bf16  144 KB (A lo)
    //   [0x080000, 0x23C000)  offf  fp32  1.77 MB
    //   [0x240000, 0x360000)  wregb bf16  1.18 MB ([o][t*256+c] order)
    //   [0x400000, 0x1400000) xt    fp32  16 MB  (channel-last x)
    u16*   wph   = (u16*)(ws);
    u16*   wpl   = (u16*)(ws + 0x40000u);
    float* offf  = (float*)(ws + 0x80000u);
    u16*   wregb = (u16*)(ws + 0x240000u);
    float* xt    = (float*)(ws + 0x400000u);

    kprep<<<288,  256, 0, stream>>>(woff, wmod, wph, wpl);
    kwreg<<<2304, 256, 0, stream>>>(wreg, wregb);
    ktrans<<<dim3(64, 4, 4), 256, 0, stream>>>(x, xt);
    koffg<<<512,  256, 0, stream>>>(xt, wph, wpl, boff, bmod, offf);
    kfused<<<256, 512, 0, stream>>>(xt, offf, wregb, gamma, beta,
                                    rmean, rvar, out);
}

// Round 10
// 191.232 us; speedup vs baseline: 1.2994x; 1.1706x over previous
//
#include <hip/hip_runtime.h>
#include <hip/hip_bf16.h>

typedef unsigned short u16;
typedef unsigned int   u32;
typedef short   bf16x8 __attribute__((ext_vector_type(8)));  // bf16 carried as i16
typedef float   f32x4  __attribute__((ext_vector_type(4)));

__device__ __forceinline__ float bf2f(u16 u) {
    u32 t = ((u32)u) << 16;
    return __builtin_bit_cast(float, t);
}
__device__ __forceinline__ u32 f2bf(float f) {
    u32 u = __builtin_bit_cast(u32, f);
    return (u + 0x7FFFu + ((u >> 16) & 1u)) >> 16;   // RNE
}
// async global->LDS DMA, 16 B per lane (dst = wave-uniform base + lane*16)
__device__ __forceinline__ void load_lds16(const u16* g, u16* l) {
    __builtin_amdgcn_global_load_lds(
        (const __attribute__((address_space(1))) u32*)(const void*)g,
        (__attribute__((address_space(3))) u32*)(void*)l, 16, 0, 0);
}
// Inline-asm loads (saddr form): compiler cannot sink these or auto-wait on
// them -> true async issue, paired with manual vmcnt (rule #18).
// ALL loads 16B-aligned dwordx4 (no alignment hazards).
__device__ __forceinline__ uint4 gload4(const u16* sbase, u32 voff) {
    uint4 r;
    asm volatile("global_load_dwordx4 %0, %1, %2"
                 : "=v"(r) : "v"(voff), "s"(sbase) : "memory");
    return r;
}
__device__ __forceinline__ f32x4 gload4f(const float* sbase, u32 voff) {
    f32x4 r;
    asm volatile("global_load_dwordx4 %0, %1, %2"
                 : "=v"(r) : "v"(voff), "s"(sbase) : "memory");
    return r;
}
#define WAITVM(N) do { asm volatile("s_waitcnt vmcnt(" #N ")" ::: "memory"); \
                       __builtin_amdgcn_sched_barrier(0); } while (0)

// ---------------------------------------------------------------------------
// GLOBAL K-ORDER (both GEMMs): r = t*256 + c  (tap-major).
// XCD swizzle (verified r6: FETCH 289->14.6 MB): xcd = bid&7 -> row band.
// Channel-last xt[b][pixel][c] (r8, verified). r10 = BISECTION:
//   koffg = r8-exact (verified 1-deep pipeline)
//   kfused = r9 divergence-aware gather lane remap (formally verified 3x)
// ---------------------------------------------------------------------------

// Kernel 0a: offset/mask conv weights -> hi/lo bf16 A[32][2304], r = t*256+c
__global__ void kprep(const float* __restrict__ woff, const float* __restrict__ wmod,
                      u16* __restrict__ ah, u16* __restrict__ al) {
    int i = blockIdx.x * 256 + threadIdx.x;      // 288 blocks -> 73728 exact
    if (i >= 32 * 2304) return;
    int oc = i / 2304, r = i - oc * 2304;
    int t = r >> 8, c = r & 255;
    float v = 0.f;
    if (oc < 18)      v = woff[oc * 2304 + c * 9 + t];
    else if (oc < 27) v = wmod[(oc - 18) * 2304 + c * 9 + t];
    u32 hb = f2bf(v);
    u32 lb = f2bf(v - bf2f((u16)hb));
    ah[i] = (u16)hb;
    al[i] = (u16)lb;
}

// Kernel 0b: w_reg f32 -> bf16, layout [o][t*256+c] (matches gather K-order).
__global__ void kwreg(const float* __restrict__ wreg, u16* __restrict__ wregb) {
    int i = blockIdx.x * 256 + threadIdx.x;      // 2304 blocks exact
    int o = i / 2304, r = i - o * 2304;
    int t = r >> 8, c = r & 255;
    wregb[i] = (u16)f2bf(wreg[o * 2304 + c * 9 + t]);
}

// Kernel 0c: transpose x[b][c][p] -> xt[b][p][c]  (channel-last, 16 MB).
__global__ __launch_bounds__(256) void ktrans(const float* __restrict__ x,
                                              float* __restrict__ xt) {
    __shared__ float T[64][65];
    int t = threadIdx.x;
    int pl = t & 63, cr = t >> 6;                // 4 rows per pass
    int p0 = blockIdx.x * 64;                    // pixel tile
    int c0 = blockIdx.y * 64;                    // channel tile
    int b  = blockIdx.z;
    const float* xb  = x  + ((long)b << 20);
    float*       xtb = xt + ((long)b << 20);
#pragma unroll
    for (int i = 0; i < 16; i++) {
        int c = cr + i * 4;
        T[c][pl] = xb[((long)(c0 + c) << 12) + p0 + pl];
    }
    __syncthreads();
#pragma unroll
    for (int i = 0; i < 16; i++) {
        int p = cr + i * 4;
        xtb[(long)(p0 + p) * 256 + c0 + pl] = T[pl][p];
    }
}

// ---------------------------------------------------------------------------
// Kernel 1: offset/mask conv as MFMA GEMM, M=32 (27 live), N=16384, K=2304.
// r8-EXACT (verified): 1-deep pipeline, asm loads in flight over MFMA,
// WAITVM(0) before stores, one barrier per kt. B from xt (2x dwordx4).
// ---------------------------------------------------------------------------
__global__ __launch_bounds__(256) void koffg(const float* __restrict__ xt,
                                             const u16* __restrict__ ah_g,
                                             const u16* __restrict__ al_g,
                                             const float* __restrict__ boff,
                                             const float* __restrict__ bmod,
                                             float* __restrict__ offf) {
    __shared__ u16 Ah[2][32 * 72], Al[2][32 * 72]; // 32 oc-rows, 64 k + 8 pad
    __shared__ u16 Bh[2][32 * 72], Bl[2][32 * 72]; // 32 n-rows,  64 k + 8 pad
    int tid = threadIdx.x;
    // XCD swizzle: 512 blocks, xcd = bid&7 -> (img, band), j -> row/half
    int bid = blockIdx.x;
    int xcd = bid & 7, j = bid >> 3;             // j in [0,64)
    int img = xcd >> 1;
    int row = ((xcd & 1) << 5) + (j >> 1);
    int n0 = ((img << 6) + row) * 64 + (j & 1) * 32;
    int b = n0 >> 12, h0 = (n0 & 4095) >> 6, w0 = n0 & 63;
    int lane = tid & 63, wv = tid >> 6;
    int mt = wv & 1, nt = wv >> 1;               // 2 m-tiles x 2 n-tiles of 16
    int col = lane & 15, quad = lane >> 4;

    int aoc = tid >> 3, ak0 = (tid & 7) * 8;     // A staging role
    int nl = tid & 31, cl0 = (tid >> 5) * 8;     // B staging role

    const float* xtb = xt + ((long)b << 20);     // image base (SGPR)
    u32 avoff0 = (u32)(aoc * 2304 + ak0) * 2;    // bytes into ah_g/al_g

    f32x4 acc = (f32x4){0.f, 0.f, 0.f, 0.f};

    uint4 pah, pal;
    f32x4 xw0, xw1;
    bool  vm;

    auto issue = [&](int kt) {                   // 4 asm loads, stay in flight
        int t = kt >> 2, c0 = (kt & 3) << 6, r0 = kt * 64;
        int dy = t / 3 - 1, dx = t % 3 - 1;
        pah = gload4(ah_g, avoff0 + (u32)r0 * 2);
        pal = gload4(al_g, avoff0 + (u32)r0 * 2);
        int hp = h0 + dy, wp = w0 + nl + dx;
        vm = ((unsigned)hp < 64u) && ((unsigned)wp < 64u);
        int hc = min(max(hp, 0), 63), wc = min(max(wp, 0), 63);
        u32 pixb = (u32)(hc * 64 + wc) << 10;    // pixel record (1 KB)
        u32 cb   = (u32)(c0 + cl0) << 2;         // channel byte offset (32B-al)
        xw0 = gload4f(xtb, pixb + cb);           // ch c..c+3
        xw1 = gload4f(xtb, pixb + cb + 16);      // ch c+4..c+7
    };
    auto stores = [&](int buf) {                 // after WAITVM(0)
        u32 whi[4], wlo[4];
#pragma unroll
        for (int i = 0; i < 8; i++) {
            float xvi = (i < 4) ? xw0[i] : xw1[i - 4];
            float v = vm ? xvi : 0.f;
            u32 hb = f2bf(v);
            u32 lb = f2bf(v - bf2f((u16)hb));
            if (i & 1) { whi[i >> 1] |= hb << 16; wlo[i >> 1] |= lb << 16; }
            else       { whi[i >> 1]  = hb;       wlo[i >> 1]  = lb; }
        }
        *(uint4*)&Ah[buf][aoc * 72 + ak0] = pah;
        *(uint4*)&Al[buf][aoc * 72 + ak0] = pal;
        *(uint4*)&Bh[buf][nl * 72 + cl0] = make_uint4(whi[0], whi[1], whi[2], whi[3]);
        *(uint4*)&Bl[buf][nl * 72 + cl0] = make_uint4(wlo[0], wlo[1], wlo[2], wlo[3]);
    };

    issue(0);
    WAITVM(0);
    stores(0);
    __syncthreads();

    for (int kt = 0; kt < 36; kt++) {
        int cur = kt & 1, nxt = kt + 1;
        if (nxt < 36) issue(nxt);                // in flight over MFMA phase
#pragma unroll
        for (int ks = 0; ks < 2; ks++) {
            int ko = ks * 32 + quad * 8;
            bf16x8 fah = *(const bf16x8*)&Ah[cur][(mt * 16 + col) * 72 + ko];
            bf16x8 fal = *(const bf16x8*)&Al[cur][(mt * 16 + col) * 72 + ko];
            bf16x8 fbh = *(const bf16x8*)&Bh[cur][(nt * 16 + col) * 72 + ko];
            bf16x8 fbl = *(const bf16x8*)&Bl[cur][(nt * 16 + col) * 72 + ko];
            acc = __builtin_amdgcn_mfma_f32_16x16x32_bf16(fah, fbh, acc, 0, 0, 0);
            acc = __builtin_amdgcn_mfma_f32_16x16x32_bf16(fah, fbl, acc, 0, 0, 0);
            acc = __builtin_amdgcn_mfma_f32_16x16x32_bf16(fal, fbh, acc, 0, 0, 0);
        }
        if (nxt < 36) {
            WAITVM(0);                           // loads done; latency hidden
            stores(nxt & 1);
        }
        __syncthreads();                         // one barrier per kt
    }

    int n = n0 + nt * 16 + col;
#pragma unroll
    for (int r = 0; r < 4; r++) {
        int oc = mt * 16 + quad * 4 + r;
        float s = acc[r];
        if (oc < 18) {
            int ch = 3 * (oc >> 1) + (oc & 1);   // even oc -> dy, odd -> dx
            offf[(ch << 14) + n] = s + boff[oc];
        } else if (oc < 27) {
            float tt = s + bmod[oc - 18];
            int ch = 3 * (oc - 18) + 2;
            offf[(ch << 14) + n] = 2.f / (1.f + __expf(-tt));
        }
    }
}

// ---------------------------------------------------------------------------
// Kernel 2 (FUSED): sampling + GEMM + BN + ReLU.  r9 divergence-aware
// gather lane map (kept for bisection). Wave = 4 pixel-slots x 16 ch-quads;
// each thread owns 2 pixels and loads one dwordx4 per (pixel, neighbor):
// 16-lane groups read 256B contiguous from one record -> 16 cachelines per
// wave-instr (was 64). 8 gather instrs/thread-kt; combine + 8B Sl writes.
// Same values, combine order, bf16 rounding as r8.
// ---------------------------------------------------------------------------
__global__ __launch_bounds__(512, 2) void kfused(const float* __restrict__ xt,
                                                 const float* __restrict__ offf,
                                                 const u16* __restrict__ wregb,
                                                 const float* __restrict__ gamma,
                                                 const float* __restrict__ beta,
                                                 const float* __restrict__ rmean,
                                                 const float* __restrict__ rvar,
                                                 float* __restrict__ out) {
    __shared__ u16 Wl[2][256 * 64];  // [buf][o][k] granule-XOR-swizzled, 64 KB
    __shared__ u16 Sl[2][8 * 64 * 8];// [buf][c-octet][n][8ch], 16 KB
    int tid = threadIdx.x;
    int lane = tid & 63, wv = tid >> 6;
    int pxs = lane >> 4, chq = lane & 15;        // pixel-slot, channel-quad
    // XCD swizzle: 256 blocks -> xcd gets a 32-row band of one image
    int bid = blockIdx.x;
    int xcd = bid & 7;
    int bb  = xcd >> 1;                          // image   (block-uniform)
    int h   = ((xcd & 1) << 5) + (bid >> 3);     // row     (block-uniform)
    int nbase = ((bb << 6) + h) * 64;            // first pixel of this row
    int wo = (wv >> 1) * 64, wn = (wv & 1) * 32; // wave output tile 64o x 32n
    int col = lane & 15, quad = lane >> 4;

    int px0 = wv * 8 + pxs;                      // gather batch-0 pixel
    int px1 = wv * 8 + 4 + pxs;                  // gather batch-1 pixel

    const float* xb = xt + ((long)bb << 20);     // image base (SGPR)

    f32x4 acc[4][2];
#pragma unroll
    for (int i = 0; i < 4; i++)
#pragma unroll
        for (int j = 0; j < 2; j++) acc[i][j] = (f32x4){0.f, 0.f, 0.f, 0.f};

    u32   pb0[4], pb1[4];                        // neighbor record byte offs
    float sw0[4], sw1[4];                        // bilinear*mask weights
    f32x4 g0[4], g1[4];                          // in-flight 4ch quads

    auto tapcomp = [&](int t, int pxi, u32 (&pb)[4], float (&sw)[4]) {
        int n = nbase + pxi;
        int g = t / 3, tx = t - 3 * g;
        float dy = offf[((3 * t + 0) << 14) + n];
        float dx = offf[((3 * t + 1) << 14) + n];
        float m  = offf[((3 * t + 2) << 14) + n];
        float py = (float)(h - 1 + g) + dy;
        float px = (float)(pxi - 1 + tx) + dx;
        float y0f = floorf(py), x0f = floorf(px);
        float wy = py - y0f, wx = px - x0f;
        int iy0 = (int)y0f, ix0 = (int)x0f;
        int iy1 = iy0 + 1, ix1 = ix0 + 1;
        bool vy0 = (unsigned)iy0 < 64u, vy1 = (unsigned)iy1 < 64u;
        bool vx0 = (unsigned)ix0 < 64u, vx1 = (unsigned)ix1 < 64u;
        int cy0 = min(max(iy0, 0), 63), cy1 = min(max(iy1, 0), 63);
        int cx0 = min(max(ix0, 0), 63), cx1 = min(max(ix1, 0), 63);
        pb[0] = (u32)(cy0 * 64 + cx0) << 10; pb[1] = (u32)(cy0 * 64 + cx1) << 10;
        pb[2] = (u32)(cy1 * 64 + cx0) << 10; pb[3] = (u32)(cy1 * 64 + cx1) << 10;
        float a = 1.f - wy, bw = 1.f - wx;
        sw[0] = (vy0 && vx0) ? a  * bw * m : 0.f;
        sw[1] = (vy0 && vx1) ? a  * wx * m : 0.f;
        sw[2] = (vy1 && vx0) ? wy * bw * m : 0.f;
        sw[3] = (vy1 && vx1) ? wy * wx * m : 0.f;
    };
    auto gissue = [&](int kt) {                  // 8 dwordx4, 16 cachelines ea
        u32 co = ((u32)(kt & 3) << 8) + (u32)chq * 16;
#pragma unroll
        for (int nb = 0; nb < 4; nb++) g0[nb] = gload4f(xb, pb0[nb] + co);
#pragma unroll
        for (int nb = 0; nb < 4; nb++) g1[nb] = gload4f(xb, pb1[nb] + co);
    };
    auto dmaA = [&](int kt, int buf) {           // async A staging, 32 KB
#pragma unroll
        for (int i = 0; i < 4; i++) {
            int cidx = tid + i * 512;
            int o = cidx >> 3, qp = cidx & 7;
            int ql = qp ^ (o & 7);               // source-side XOR swizzle
            load_lds16(wregb + (long)o * 2304 + kt * 64 + ql * 8,
                       &Wl[buf][cidx * 8]);
        }
    };
    auto bwrite = [&](int buf) {                 // combine + pack + 8B writes
        f32x4 v = sw0[0] * g0[0] + sw0[1] * g0[1] + sw0[2] * g0[2] + sw0[3] * g0[3];
        u32 w0 = f2bf(v[0]) | (f2bf(v[1]) << 16);
        u32 w1 = f2bf(v[2]) | (f2bf(v[3]) << 16);
        *(uint2*)&Sl[buf][((chq >> 1) * 64 + px0) * 8 + (chq & 1) * 4] =
            make_uint2(w0, w1);
        v = sw1[0] * g1[0] + sw1[1] * g1[1] + sw1[2] * g1[2] + sw1[3] * g1[3];
        w0 = f2bf(v[0]) | (f2bf(v[1]) << 16);
        w1 = f2bf(v[2]) | (f2bf(v[3]) << 16);
        *(uint2*)&Sl[buf][((chq >> 1) * 64 + px1) * 8 + (chq & 1) * 4] =
            make_uint2(w0, w1);
    };

    // prologue: fill buffer 0
    tapcomp(0, px0, pb0, sw0);
    tapcomp(0, px1, pb1, sw1);
    gissue(0);
    dmaA(0, 0);
    WAITVM(0);
    bwrite(0);
    __syncthreads();

    for (int kt = 0; kt < 36; kt++) {
        int cur = kt & 1, nxt = kt + 1;
        if (nxt < 36) {
            if ((nxt & 3) == 0) {
                tapcomp(nxt >> 2, px0, pb0, sw0);
                tapcomp(nxt >> 2, px1, pb1, sw1);
            }
            gissue(nxt);                         // 8 oldest outstanding vmem
            dmaA(nxt, nxt & 1);                  // 4 newest (drain at barrier)
        }
#pragma unroll
        for (int ks = 0; ks < 2; ks++) {
            bf16x8 af[4], bfr[2];
#pragma unroll
            for (int i = 0; i < 4; i++) {
                int r = wo + i * 16 + col;
                int ph = (ks * 4 + quad) ^ (r & 7);
                af[i] = *(const bf16x8*)&Wl[cur][r * 64 + ph * 8];
            }
#pragma unroll
            for (int j = 0; j < 2; j++)
                bfr[j] = *(const bf16x8*)&Sl[cur][((ks * 4 + quad) * 64 +
                                                   (wn + j * 16 + col)) * 8];
#pragma unroll
            for (int i = 0; i < 4; i++)
#pragma unroll
                for (int j = 0; j < 2; j++)
                    acc[i][j] = __builtin_amdgcn_mfma_f32_16x16x32_bf16(
                        af[i], bfr[j], acc[i][j], 0, 0, 0);
        }
        if (nxt < 36) {
            WAITVM(4);                           // gathers done, DMA may fly
            bwrite(nxt & 1);
        }
        __syncthreads();                         // drains DMA + ds_write; one/kt
    }

    // epilogue: BN + ReLU, D layout: row(o) = quad*4+reg, col(n) = lane&15
#pragma unroll
    for (int i = 0; i < 4; i++) {
        int ob = wo + i * 16 + quad * 4;
        float inv[4], add[4];
#pragma unroll
        for (int r = 0; r < 4; r++) {
            int o = ob + r;
            float iv = gamma[o] * rsqrtf(rvar[o] + 1e-5f);
            inv[r] = iv; add[r] = beta[o] - rmean[o] * iv;
        }
#pragma unroll
        for (int j = 0; j < 2; j++) {
            int n_g = nbase + wn + j * 16 + col;
            int bq = n_g >> 12, hw = n_g & 4095;
            float* op = out + ((long)bq << 20) + hw;
#pragma unroll
            for (int r = 0; r < 4; r++) {
                float v = acc[i][j][r] * inv[r] + add[r];
                v = fmaxf(v, 0.f);
                op[(long)(ob + r) << 12] = v;
            }
        }
    }
}

// ---------------------------------------------------------------------------
extern "C" void kernel_launch(void* const* d_in, const int* in_sizes, int n_in,
                              void* d_out, int out_size, void* d_ws, size_t ws_size,
                              hipStream_t stream) {
    const float* x     = (const float*)d_in[0];
    const float* woff  = (const float*)d_in[1];
    const float* boff  = (const float*)d_in[2];
    const float* wmod  = (const float*)d_in[3];
    const float* bmod  = (const float*)d_in[4];
    const float* wreg  = (const float*)d_in[5];
    const float* gamma = (const float*)d_in[6];
    const float* beta  = (const float*)d_in[7];
    const float* rmean = (const float*)d_in[8];
    const float* rvar  = (const float*)d_in[9];
    float* out = (float*)d_out;

    char* ws = (char*)d_ws;
    // ws map:
    //   [0x000000, 0x024000)  wph   bf16  144 KB (A hi, koffg)
    //   [0x040000, 0x064000)  wpl   bf16  144 KB (A lo)
    //   [0x080000, 0x23C000)  offf  fp32  1.77 MB
    //   [0x240000, 0x360000)  wregb bf16  1.18 MB ([o][t*256+c] order)
    //   [0x400000, 0x1400000) xt    fp32  16 MB  (channel-last x)
    u16*   wph   = (u16*)(ws);
    u16*   wpl   = (u16*)(ws + 0x40000u);
    float* offf  = (float*)(ws + 0x80000u);
    u16*   wregb = (u16*)(ws + 0x240000u);
    float* xt    = (float*)(ws + 0x400000u);

    kprep<<<288,  256, 0, stream>>>(woff, wmod, wph, wpl);
    kwreg<<<2304, 256, 0, stream>>>(wreg, wregb);
    ktrans<<<dim3(64, 4, 4), 256, 0, stream>>>(x, xt);
    koffg<<<512,  256, 0, stream>>>(xt, wph, wpl, boff, bmod, offf);
    kfused<<<256, 512, 0, stream>>>(xt, offf, wregb, gamma, beta,
                                    rmean, rvar, out);
}

// Round 12
// 185.485 us; speedup vs baseline: 1.3397x; 1.0310x over previous
//
#include <hip/hip_runtime.h>
#include <hip/hip_bf16.h>

typedef unsigned short u16;
typedef unsigned int   u32;
typedef short   bf16x8 __attribute__((ext_vector_type(8)));  // bf16 carried as i16
typedef float   f32x4  __attribute__((ext_vector_type(4)));

__device__ __forceinline__ float bf2f(u16 u) {
    u32 t = ((u32)u) << 16;
    return __builtin_bit_cast(float, t);
}
__device__ __forceinline__ u32 f2bf(float f) {
    u32 u = __builtin_bit_cast(u32, f);
    return (u + 0x7FFFu + ((u >> 16) & 1u)) >> 16;   // RNE
}
// async global->LDS DMA, 16 B per lane (dst = wave-uniform base + lane*16)
__device__ __forceinline__ void load_lds16(const u16* g, u16* l) {
    __builtin_amdgcn_global_load_lds(
        (const __attribute__((address_space(1))) u32*)(const void*)g,
        (__attribute__((address_space(3))) u32*)(void*)l, 16, 0, 0);
}
// Inline-asm loads (saddr form): compiler cannot sink these or auto-wait on
// them -> true async issue, paired with manual vmcnt (rule #18).
// ALL loads 16B-aligned dwordx4 (no alignment hazards).
__device__ __forceinline__ uint4 gload4(const u16* sbase, u32 voff) {
    uint4 r;
    asm volatile("global_load_dwordx4 %0, %1, %2"
                 : "=v"(r) : "v"(voff), "s"(sbase) : "memory");
    return r;
}
__device__ __forceinline__ f32x4 gload4f(const float* sbase, u32 voff) {
    f32x4 r;
    asm volatile("global_load_dwordx4 %0, %1, %2"
                 : "=v"(r) : "v"(voff), "s"(sbase) : "memory");
    return r;
}
#define WAITVM(N) do { asm volatile("s_waitcnt vmcnt(" #N ")" ::: "memory"); \
                       __builtin_amdgcn_sched_barrier(0); } while (0)

// ---------------------------------------------------------------------------
// GLOBAL K-ORDER (both GEMMs): r = t*256 + c  (tap-major).
// XCD swizzle (verified r6: FETCH 289->14.6 MB): xcd = bid&7 -> row band.
// Channel-last xt[b][pixel][c] (r8). kfused divergence-aware gather map
// (r9/r10 verified: 104.6 -> 67.8 us). r12: koffg T4 restructure with the
// r11 LDS-index typo fixed (stores(nxt) -> stores(nxt & 1)). Loads stay in
// flight across a raw s_barrier (no vmcnt drain).
// ---------------------------------------------------------------------------

// Kernel 0a: offset/mask conv weights -> hi/lo bf16 A[32][2304], r = t*256+c
__global__ void kprep(const float* __restrict__ woff, const float* __restrict__ wmod,
                      u16* __restrict__ ah, u16* __restrict__ al) {
    int i = blockIdx.x * 256 + threadIdx.x;      // 288 blocks -> 73728 exact
    if (i >= 32 * 2304) return;
    int oc = i / 2304, r = i - oc * 2304;
    int t = r >> 8, c = r & 255;
    float v = 0.f;
    if (oc < 18)      v = woff[oc * 2304 + c * 9 + t];
    else if (oc < 27) v = wmod[(oc - 18) * 2304 + c * 9 + t];
    u32 hb = f2bf(v);
    u32 lb = f2bf(v - bf2f((u16)hb));
    ah[i] = (u16)hb;
    al[i] = (u16)lb;
}

// Kernel 0b: w_reg f32 -> bf16, layout [o][t*256+c] (matches gather K-order).
__global__ void kwreg(const float* __restrict__ wreg, u16* __restrict__ wregb) {
    int i = blockIdx.x * 256 + threadIdx.x;      // 2304 blocks exact
    int o = i / 2304, r = i - o * 2304;
    int t = r >> 8, c = r & 255;
    wregb[i] = (u16)f2bf(wreg[o * 2304 + c * 9 + t]);
}

// Kernel 0c: transpose x[b][c][p] -> xt[b][p][c]  (channel-last, 16 MB).
__global__ __launch_bounds__(256) void ktrans(const float* __restrict__ x,
                                              float* __restrict__ xt) {
    __shared__ float T[64][65];
    int t = threadIdx.x;
    int pl = t & 63, cr = t >> 6;                // 4 rows per pass
    int p0 = blockIdx.x * 64;                    // pixel tile
    int c0 = blockIdx.y * 64;                    // channel tile
    int b  = blockIdx.z;
    const float* xb  = x  + ((long)b << 20);
    float*       xtb = xt + ((long)b << 20);
#pragma unroll
    for (int i = 0; i < 16; i++) {
        int c = cr + i * 4;
        T[c][pl] = xb[((long)(c0 + c) << 12) + p0 + pl];
    }
    __syncthreads();
#pragma unroll
    for (int i = 0; i < 16; i++) {
        int p = cr + i * 4;
        xtb[(long)(p0 + p) * 256 + c0 + pl] = T[pl][p];
    }
}

// ---------------------------------------------------------------------------
// Kernel 1: offset/mask conv as MFMA GEMM, M=32 (27 live), N=16384, K=2304.
// r12 T4 restructure (single register set, 1-deep), typo-fixed:
//   loop kt: mfma(cur) -> WAITVM(0) [batch nxt arrived] -> stores(nxt & 1)
//   -> issue(nxt+1) [flies across barrier] -> lgkmcnt(0) -> RAW s_barrier.
// Hazards: buf b written at kt was last read during kt-1's MFMA (before the
// kt-1 barrier); cross-barrier loads touch only registers consumed before
// re-issue; lgkmcnt(0) publishes ds_writes.
// ---------------------------------------------------------------------------
__global__ __launch_bounds__(256) void koffg(const float* __restrict__ xt,
                                             const u16* __restrict__ ah_g,
                                             const u16* __restrict__ al_g,
                                             const float* __restrict__ boff,
                                             const float* __restrict__ bmod,
                                             float* __restrict__ offf) {
    __shared__ u16 Ah[2][32 * 72], Al[2][32 * 72]; // 32 oc-rows, 64 k + 8 pad
    __shared__ u16 Bh[2][32 * 72], Bl[2][32 * 72]; // 32 n-rows,  64 k + 8 pad
    int tid = threadIdx.x;
    // XCD swizzle: 512 blocks, xcd = bid&7 -> (img, band), j -> row/half
    int bid = blockIdx.x;
    int xcd = bid & 7, j = bid >> 3;             // j in [0,64)
    int img = xcd >> 1;
    int row = ((xcd & 1) << 5) + (j >> 1);
    int n0 = ((img << 6) + row) * 64 + (j & 1) * 32;
    int b = n0 >> 12, h0 = (n0 & 4095) >> 6, w0 = n0 & 63;
    int lane = tid & 63, wv = tid >> 6;
    int mt = wv & 1, nt = wv >> 1;               // 2 m-tiles x 2 n-tiles of 16
    int col = lane & 15, quad = lane >> 4;

    int aoc = tid >> 3, ak0 = (tid & 7) * 8;     // A staging role
    int nl = tid & 31, cl0 = (tid >> 5) * 8;     // B staging role

    const float* xtb = xt + ((long)b << 20);     // image base (SGPR)
    u32 avoff0 = (u32)(aoc * 2304 + ak0) * 2;    // bytes into ah_g/al_g

    f32x4 acc = (f32x4){0.f, 0.f, 0.f, 0.f};

    uint4 pah, pal;
    f32x4 xw0, xw1;
    bool  vm;

    auto issue = [&](int kt) {                   // 4 asm loads, stay in flight
        int t = kt >> 2, c0 = (kt & 3) << 6, r0 = kt * 64;
        int dy = t / 3 - 1, dx = t % 3 - 1;
        pah = gload4(ah_g, avoff0 + (u32)r0 * 2);
        pal = gload4(al_g, avoff0 + (u32)r0 * 2);
        int hp = h0 + dy, wp = w0 + nl + dx;
        vm = ((unsigned)hp < 64u) && ((unsigned)wp < 64u);
        int hc = min(max(hp, 0), 63), wc = min(max(wp, 0), 63);
        u32 pixb = (u32)(hc * 64 + wc) << 10;    // pixel record (1 KB)
        u32 cb   = (u32)(c0 + cl0) << 2;         // channel byte offset (32B-al)
        xw0 = gload4f(xtb, pixb + cb);           // ch c..c+3
        xw1 = gload4f(xtb, pixb + cb + 16);      // ch c+4..c+7
    };
    auto stores = [&](int buf) {                 // after WAITVM(0); buf in {0,1}
        u32 whi[4], wlo[4];
#pragma unroll
        for (int i = 0; i < 8; i++) {
            float xvi = (i < 4) ? xw0[i] : xw1[i - 4];
            float v = vm ? xvi : 0.f;
            u32 hb = f2bf(v);
            u32 lb = f2bf(v - bf2f((u16)hb));
            if (i & 1) { whi[i >> 1] |= hb << 16; wlo[i >> 1] |= lb << 16; }
            else       { whi[i >> 1]  = hb;       wlo[i >> 1]  = lb; }
        }
        *(uint4*)&Ah[buf][aoc * 72 + ak0] = pah;
        *(uint4*)&Al[buf][aoc * 72 + ak0] = pal;
        *(uint4*)&Bh[buf][nl * 72 + cl0] = make_uint4(whi[0], whi[1], whi[2], whi[3]);
        *(uint4*)&Bl[buf][nl * 72 + cl0] = make_uint4(wlo[0], wlo[1], wlo[2], wlo[3]);
    };

    // prologue: batch 0 loaded+stored; batch 1 issued, flies across barrier
    issue(0);
    WAITVM(0);
    stores(0);
    issue(1);
    asm volatile("s_waitcnt lgkmcnt(0)" ::: "memory");
    __builtin_amdgcn_s_barrier();
    __builtin_amdgcn_sched_barrier(0);

    for (int kt = 0; kt < 36; kt++) {
        int cur = kt & 1, nxt = kt + 1;
#pragma unroll
        for (int ks = 0; ks < 2; ks++) {
            int ko = ks * 32 + quad * 8;
            bf16x8 fah = *(const bf16x8*)&Ah[cur][(mt * 16 + col) * 72 + ko];
            bf16x8 fal = *(const bf16x8*)&Al[cur][(mt * 16 + col) * 72 + ko];
            bf16x8 fbh = *(const bf16x8*)&Bh[cur][(nt * 16 + col) * 72 + ko];
            bf16x8 fbl = *(const bf16x8*)&Bl[cur][(nt * 16 + col) * 72 + ko];
            acc = __builtin_amdgcn_mfma_f32_16x16x32_bf16(fah, fbh, acc, 0, 0, 0);
            acc = __builtin_amdgcn_mfma_f32_16x16x32_bf16(fah, fbl, acc, 0, 0, 0);
            acc = __builtin_amdgcn_mfma_f32_16x16x32_bf16(fal, fbh, acc, 0, 0, 0);
        }
        if (nxt < 36) {
            WAITVM(0);                           // batch nxt arrived (long window)
            stores(nxt & 1);                     // ds_write buf nxt&1  [r11 FIX]
            if (nxt + 1 < 36) issue(nxt + 1);    // flies across the barrier
        }
        asm volatile("s_waitcnt lgkmcnt(0)" ::: "memory");  // my ds_writes done
        __builtin_amdgcn_s_barrier();            // RAW barrier: no vmcnt drain
        __builtin_amdgcn_sched_barrier(0);
    }

    int n = n0 + nt * 16 + col;
#pragma unroll
    for (int r = 0; r < 4; r++) {
        int oc = mt * 16 + quad * 4 + r;
        float s = acc[r];
        if (oc < 18) {
            int ch = 3 * (oc >> 1) + (oc & 1);   // even oc -> dy, odd -> dx
            offf[(ch << 14) + n] = s + boff[oc];
        } else if (oc < 27) {
            float tt = s + bmod[oc - 18];
            int ch = 3 * (oc - 18) + 2;
            offf[(ch << 14) + n] = 2.f / (1.f + __expf(-tt));
        }
    }
}

// ---------------------------------------------------------------------------
// Kernel 2 (FUSED): sampling + GEMM + BN + ReLU.  r10-EXACT (verified
// 67.8 us): divergence-aware gather lane map, 16 cachelines/wave-instr.
// Known next fix (queued): Sl uint2 writes are ~8-way bank-conflicted
// (SQ_LDS_BANK_CONFLICT 4.13M) — XOR swizzle planned once r12 verdict lands.
// ---------------------------------------------------------------------------
__global__ __launch_bounds__(512, 2) void kfused(const float* __restrict__ xt,
                                                 const float* __restrict__ offf,
                                                 const u16* __restrict__ wregb,
                                                 const float* __restrict__ gamma,
                                                 const float* __restrict__ beta,
                                                 const float* __restrict__ rmean,
                                                 const float* __restrict__ rvar,
                                                 float* __restrict__ out) {
    __shared__ u16 Wl[2][256 * 64];  // [buf][o][k] granule-XOR-swizzled, 64 KB
    __shared__ u16 Sl[2][8 * 64 * 8];// [buf][c-octet][n][8ch], 16 KB
    int tid = threadIdx.x;
    int lane = tid & 63, wv = tid >> 6;
    int pxs = lane >> 4, chq = lane & 15;        // pixel-slot, channel-quad
    // XCD swizzle: 256 blocks -> xcd gets a 32-row band of one image
    int bid = blockIdx.x;
    int xcd = bid & 7;
    int bb  = xcd >> 1;                          // image   (block-uniform)
    int h   = ((xcd & 1) << 5) + (bid >> 3);     // row     (block-uniform)
    int nbase = ((bb << 6) + h) * 64;            // first pixel of this row
    int wo = (wv >> 1) * 64, wn = (wv & 1) * 32; // wave output tile 64o x 32n
    int col = lane & 15, quad = lane >> 4;

    int px0 = wv * 8 + pxs;                      // gather batch-0 pixel
    int px1 = wv * 8 + 4 + pxs;                  // gather batch-1 pixel

    const float* xb = xt + ((long)bb << 20);     // image base (SGPR)

    f32x4 acc[4][2];
#pragma unroll
    for (int i = 0; i < 4; i++)
#pragma unroll
        for (int j = 0; j < 2; j++) acc[i][j] = (f32x4){0.f, 0.f, 0.f, 0.f};

    u32   pb0[4], pb1[4];                        // neighbor record byte offs
    float sw0[4], sw1[4];                        // bilinear*mask weights
    f32x4 g0[4], g1[4];                          // in-flight 4ch quads

    auto tapcomp = [&](int t, int pxi, u32 (&pb)[4], float (&sw)[4]) {
        int n = nbase + pxi;
        int g = t / 3, tx = t - 3 * g;
        float dy = offf[((3 * t + 0) << 14) + n];
        float dx = offf[((3 * t + 1) << 14) + n];
        float m  = offf[((3 * t + 2) << 14) + n];
        float py = (float)(h - 1 + g) + dy;
        float px = (float)(pxi - 1 + tx) + dx;
        float y0f = floorf(py), x0f = floorf(px);
        float wy = py - y0f, wx = px - x0f;
        int iy0 = (int)y0f, ix0 = (int)x0f;
        int iy1 = iy0 + 1, ix1 = ix0 + 1;
        bool vy0 = (unsigned)iy0 < 64u, vy1 = (unsigned)iy1 < 64u;
        bool vx0 = (unsigned)ix0 < 64u, vx1 = (unsigned)ix1 < 64u;
        int cy0 = min(max(iy0, 0), 63), cy1 = min(max(iy1, 0), 63);
        int cx0 = min(max(ix0, 0), 63), cx1 = min(max(ix1, 0), 63);
        pb[0] = (u32)(cy0 * 64 + cx0) << 10; pb[1] = (u32)(cy0 * 64 + cx1) << 10;
        pb[2] = (u32)(cy1 * 64 + cx0) << 10; pb[3] = (u32)(cy1 * 64 + cx1) << 10;
        float a = 1.f - wy, bw = 1.f - wx;
        sw[0] = (vy0 && vx0) ? a  * bw * m : 0.f;
        sw[1] = (vy0 && vx1) ? a  * wx * m : 0.f;
        sw[2] = (vy1 && vx0) ? wy * bw * m : 0.f;
        sw[3] = (vy1 && vx1) ? wy * wx * m : 0.f;
    };
    auto gissue = [&](int kt) {                  // 8 dwordx4, 16 cachelines ea
        u32 co = ((u32)(kt & 3) << 8) + (u32)chq * 16;
#pragma unroll
        for (int nb = 0; nb < 4; nb++) g0[nb] = gload4f(xb, pb0[nb] + co);
#pragma unroll
        for (int nb = 0; nb < 4; nb++) g1[nb] = gload4f(xb, pb1[nb] + co);
    };
    auto dmaA = [&](int kt, int buf) {           // async A staging, 32 KB
#pragma unroll
        for (int i = 0; i < 4; i++) {
            int cidx = tid + i * 512;
            int o = cidx >> 3, qp = cidx & 7;
            int ql = qp ^ (o & 7);               // source-side XOR swizzle
            load_lds16(wregb + (long)o * 2304 + kt * 64 + ql * 8,
                       &Wl[buf][cidx * 8]);
        }
    };
    auto bwrite = [&](int buf) {                 // combine + pack + 8B writes
        f32x4 v = sw0[0] * g0[0] + sw0[1] * g0[1] + sw0[2] * g0[2] + sw0[3] * g0[3];
        u32 w0 = f2bf(v[0]) | (f2bf(v[1]) << 16);
        u32 w1 = f2bf(v[2]) | (f2bf(v[3]) << 16);
        *(uint2*)&Sl[buf][((chq >> 1) * 64 + px0) * 8 + (chq & 1) * 4] =
            make_uint2(w0, w1);
        v = sw1[0] * g1[0] + sw1[1] * g1[1] + sw1[2] * g1[2] + sw1[3] * g1[3];
        w0 = f2bf(v[0]) | (f2bf(v[1]) << 16);
        w1 = f2bf(v[2]) | (f2bf(v[3]) << 16);
        *(uint2*)&Sl[buf][((chq >> 1) * 64 + px1) * 8 + (chq & 1) * 4] =
            make_uint2(w0, w1);
    };

    // prologue: fill buffer 0
    tapcomp(0, px0, pb0, sw0);
    tapcomp(0, px1, pb1, sw1);
    gissue(0);
    dmaA(0, 0);
    WAITVM(0);
    bwrite(0);
    __syncthreads();

    for (int kt = 0; kt < 36; kt++) {
        int cur = kt & 1, nxt = kt + 1;
        if (nxt < 36) {
            if ((nxt & 3) == 0) {
                tapcomp(nxt >> 2, px0, pb0, sw0);
                tapcomp(nxt >> 2, px1, pb1, sw1);
            }
            gissue(nxt);                         // 8 oldest outstanding vmem
            dmaA(nxt, nxt & 1);                  // 4 newest (drain at barrier)
        }
#pragma unroll
        for (int ks = 0; ks < 2; ks++) {
            bf16x8 af[4], bfr[2];
#pragma unroll
            for (int i = 0; i < 4; i++) {
                int r = wo + i * 16 + col;
                int ph = (ks * 4 + quad) ^ (r & 7);
                af[i] = *(const bf16x8*)&Wl[cur][r * 64 + ph * 8];
            }
#pragma unroll
            for (int j = 0; j < 2; j++)
                bfr[j] = *(const bf16x8*)&Sl[cur][((ks * 4 + quad) * 64 +
                                                   (wn + j * 16 + col)) * 8];
#pragma unroll
            for (int i = 0; i < 4; i++)
#pragma unroll
                for (int j = 0; j < 2; j++)
                    acc[i][j] = __builtin_amdgcn_mfma_f32_16x16x32_bf16(
                        af[i], bfr[j], acc[i][j], 0, 0, 0);
        }
        if (nxt < 36) {
            WAITVM(4);                           // gathers done, DMA may fly
            bwrite(nxt & 1);
        }
        __syncthreads();                         // drains DMA + ds_write; one/kt
    }

    // epilogue: BN + ReLU, D layout: row(o) = quad*4+reg, col(n) = lane&15
#pragma unroll
    for (int i = 0; i < 4; i++) {
        int ob = wo + i * 16 + quad * 4;
        float inv[4], add[4];
#pragma unroll
        for (int r = 0; r < 4; r++) {
            int o = ob + r;
            float iv = gamma[o] * rsqrtf(rvar[o] + 1e-5f);
            inv[r] = iv; add[r] = beta[o] - rmean[o] * iv;
        }
#pragma unroll
        for (int j = 0; j < 2; j++) {
            int n_g = nbase + wn + j * 16 + col;
            int bq = n_g >> 12, hw = n_g & 4095;
            float* op = out + ((long)bq << 20) + hw;
#pragma unroll
            for (int r = 0; r < 4; r++) {
                float v = acc[i][j][r] * inv[r] + add[r];
                v = fmaxf(v, 0.f);
                op[(long)(ob + r) << 12] = v;
            }
        }
    }
}

// ---------------------------------------------------------------------------
extern "C" void kernel_launch(void* const* d_in, const int* in_sizes, int n_in,
                              void* d_out, int out_size, void* d_ws, size_t ws_size,
                              hipStream_t stream) {
    const float* x     = (const float*)d_in[0];
    const float* woff  = (const float*)d_in[1];
    const float* boff  = (const float*)d_in[2];
    const float* wmod  = (const float*)d_in[3];
    const float* bmod  = (const float*)d_in[4];
    const float* wreg  = (const float*)d_in[5];
    const float* gamma = (const float*)d_in[6];
    const float* beta  = (const float*)d_in[7];
    const float* rmean = (const float*)d_in[8];
    const float* rvar  = (const float*)d_in[9];
    float* out = (float*)d_out;

    char* ws = (char*)d_ws;
    // ws map:
    //   [0x000000, 0x024000)  wph   bf16  144 KB (A hi, koffg)
    //   [0x040000, 0x064000)  wpl   bf16  144 KB (A lo)
    //   [0x080000, 0x23C000)  offf  fp32  1.77 MB
    //   [0x240000, 0x360000)  wregb bf16  1.18 MB ([o][t*256+c] order)
    //   [0x400000, 0x1400000) xt    fp32  16 MB  (channel-last x)
    u16*   wph   = (u16*)(ws);
    u16*   wpl   = (u16*)(ws + 0x40000u);
    float* offf  = (float*)(ws + 0x80000u);
    u16*   wregb = (u16*)(ws + 0x240000u);
    float* xt    = (float*)(ws + 0x400000u);

    kprep<<<288,  256, 0, stream>>>(woff, wmod, wph, wpl);
    kwreg<<<2304, 256, 0, stream>>>(wreg, wregb);
    ktrans<<<dim3(64, 4, 4), 256, 0, stream>>>(x, xt);
    koffg<<<512,  256, 0, stream>>>(xt, wph, wpl, boff, bmod, offf);
    kfused<<<256, 512, 0, stream>>>(xt, offf, wregb, gamma, beta,
                                    rmean, rvar, out);
}

// Round 13
// 178.511 us; speedup vs baseline: 1.3920x; 1.0391x over previous
//
#include <hip/hip_runtime.h>
#include <hip/hip_bf16.h>

typedef unsigned short u16;
typedef unsigned int   u32;
typedef short   bf16x8 __attribute__((ext_vector_type(8)));  // bf16 carried as i16
typedef float   f32x4  __attribute__((ext_vector_type(4)));

__device__ __forceinline__ float bf2f(u16 u) {
    u32 t = ((u32)u) << 16;
    return __builtin_bit_cast(float, t);
}
__device__ __forceinline__ u32 f2bf(float f) {
    u32 u = __builtin_bit_cast(u32, f);
    return (u + 0x7FFFu + ((u >> 16) & 1u)) >> 16;   // RNE
}
// async global->LDS DMA, 16 B per lane (dst = wave-uniform base + lane*16)
__device__ __forceinline__ void load_lds16(const u16* g, u16* l) {
    __builtin_amdgcn_global_load_lds(
        (const __attribute__((address_space(1))) u32*)(const void*)g,
        (__attribute__((address_space(3))) u32*)(void*)l, 16, 0, 0);
}
// Inline-asm loads (saddr form): compiler cannot sink these or auto-wait on
// them -> true async issue, paired with manual vmcnt (rule #18).
// ALL loads 16B-aligned dwordx4 (no alignment hazards).
__device__ __forceinline__ uint4 gload4(const u16* sbase, u32 voff) {
    uint4 r;
    asm volatile("global_load_dwordx4 %0, %1, %2"
                 : "=v"(r) : "v"(voff), "s"(sbase) : "memory");
    return r;
}
__device__ __forceinline__ f32x4 gload4f(const float* sbase, u32 voff) {
    f32x4 r;
    asm volatile("global_load_dwordx4 %0, %1, %2"
                 : "=v"(r) : "v"(voff), "s"(sbase) : "memory");
    return r;
}
#define WAITVM(N) do { asm volatile("s_waitcnt vmcnt(" #N ")" ::: "memory"); \
                       __builtin_amdgcn_sched_barrier(0); } while (0)

// ---------------------------------------------------------------------------
// GLOBAL K-ORDER (both GEMMs): r = t*256 + c  (tap-major).
// XCD swizzle (verified r6): xcd = bid&7 -> 32-row band of one image.
// Channel-last xt[b][pixel][c] (r8). kfused divergence-aware gather map
// (r9/r10: 104.6 -> 67.8us). koffg T4 raw-barrier (r12: -13us non-kfused).
// r13: kfused 2-BLOCKS/CU — grid 512, 32 px/block, LDS 72 KB -> two blocks
// co-resident (16 waves/CU, occupancy 20->40%) to fill the latency gaps of
// the serialized gather/MFMA/pack phases. Per-pixel math unchanged.
// ---------------------------------------------------------------------------

// Kernel 0a: offset/mask conv weights -> hi/lo bf16 A[32][2304], r = t*256+c
__global__ void kprep(const float* __restrict__ woff, const float* __restrict__ wmod,
                      u16* __restrict__ ah, u16* __restrict__ al) {
    int i = blockIdx.x * 256 + threadIdx.x;      // 288 blocks -> 73728 exact
    if (i >= 32 * 2304) return;
    int oc = i / 2304, r = i - oc * 2304;
    int t = r >> 8, c = r & 255;
    float v = 0.f;
    if (oc < 18)      v = woff[oc * 2304 + c * 9 + t];
    else if (oc < 27) v = wmod[(oc - 18) * 2304 + c * 9 + t];
    u32 hb = f2bf(v);
    u32 lb = f2bf(v - bf2f((u16)hb));
    ah[i] = (u16)hb;
    al[i] = (u16)lb;
}

// Kernel 0b: w_reg f32 -> bf16, layout [o][t*256+c] (matches gather K-order).
__global__ void kwreg(const float* __restrict__ wreg, u16* __restrict__ wregb) {
    int i = blockIdx.x * 256 + threadIdx.x;      // 2304 blocks exact
    int o = i / 2304, r = i - o * 2304;
    int t = r >> 8, c = r & 255;
    wregb[i] = (u16)f2bf(wreg[o * 2304 + c * 9 + t]);
}

// Kernel 0c: transpose x[b][c][p] -> xt[b][p][c]  (channel-last, 16 MB).
__global__ __launch_bounds__(256) void ktrans(const float* __restrict__ x,
                                              float* __restrict__ xt) {
    __shared__ float T[64][65];
    int t = threadIdx.x;
    int pl = t & 63, cr = t >> 6;                // 4 rows per pass
    int p0 = blockIdx.x * 64;                    // pixel tile
    int c0 = blockIdx.y * 64;                    // channel tile
    int b  = blockIdx.z;
    const float* xb  = x  + ((long)b << 20);
    float*       xtb = xt + ((long)b << 20);
#pragma unroll
    for (int i = 0; i < 16; i++) {
        int c = cr + i * 4;
        T[c][pl] = xb[((long)(c0 + c) << 12) + p0 + pl];
    }
    __syncthreads();
#pragma unroll
    for (int i = 0; i < 16; i++) {
        int p = cr + i * 4;
        xtb[(long)(p0 + p) * 256 + c0 + pl] = T[pl][p];
    }
}

// ---------------------------------------------------------------------------
// Kernel 1: offset/mask conv as MFMA GEMM, M=32 (27 live), N=16384, K=2304.
// r12-EXACT (verified): T4 raw-barrier pipeline, stores(nxt & 1).
// ---------------------------------------------------------------------------
__global__ __launch_bounds__(256) void koffg(const float* __restrict__ xt,
                                             const u16* __restrict__ ah_g,
                                             const u16* __restrict__ al_g,
                                             const float* __restrict__ boff,
                                             const float* __restrict__ bmod,
                                             float* __restrict__ offf) {
    __shared__ u16 Ah[2][32 * 72], Al[2][32 * 72]; // 32 oc-rows, 64 k + 8 pad
    __shared__ u16 Bh[2][32 * 72], Bl[2][32 * 72]; // 32 n-rows,  64 k + 8 pad
    int tid = threadIdx.x;
    // XCD swizzle: 512 blocks, xcd = bid&7 -> (img, band), j -> row/half
    int bid = blockIdx.x;
    int xcd = bid & 7, j = bid >> 3;             // j in [0,64)
    int img = xcd >> 1;
    int row = ((xcd & 1) << 5) + (j >> 1);
    int n0 = ((img << 6) + row) * 64 + (j & 1) * 32;
    int b = n0 >> 12, h0 = (n0 & 4095) >> 6, w0 = n0 & 63;
    int lane = tid & 63, wv = tid >> 6;
    int mt = wv & 1, nt = wv >> 1;               // 2 m-tiles x 2 n-tiles of 16
    int col = lane & 15, quad = lane >> 4;

    int aoc = tid >> 3, ak0 = (tid & 7) * 8;     // A staging role
    int nl = tid & 31, cl0 = (tid >> 5) * 8;     // B staging role

    const float* xtb = xt + ((long)b << 20);     // image base (SGPR)
    u32 avoff0 = (u32)(aoc * 2304 + ak0) * 2;    // bytes into ah_g/al_g

    f32x4 acc = (f32x4){0.f, 0.f, 0.f, 0.f};

    uint4 pah, pal;
    f32x4 xw0, xw1;
    bool  vm;

    auto issue = [&](int kt) {                   // 4 asm loads, stay in flight
        int t = kt >> 2, c0 = (kt & 3) << 6, r0 = kt * 64;
        int dy = t / 3 - 1, dx = t % 3 - 1;
        pah = gload4(ah_g, avoff0 + (u32)r0 * 2);
        pal = gload4(al_g, avoff0 + (u32)r0 * 2);
        int hp = h0 + dy, wp = w0 + nl + dx;
        vm = ((unsigned)hp < 64u) && ((unsigned)wp < 64u);
        int hc = min(max(hp, 0), 63), wc = min(max(wp, 0), 63);
        u32 pixb = (u32)(hc * 64 + wc) << 10;    // pixel record (1 KB)
        u32 cb   = (u32)(c0 + cl0) << 2;         // channel byte offset (32B-al)
        xw0 = gload4f(xtb, pixb + cb);           // ch c..c+3
        xw1 = gload4f(xtb, pixb + cb + 16);      // ch c+4..c+7
    };
    auto stores = [&](int buf) {                 // after WAITVM(0); buf in {0,1}
        u32 whi[4], wlo[4];
#pragma unroll
        for (int i = 0; i < 8; i++) {
            float xvi = (i < 4) ? xw0[i] : xw1[i - 4];
            float v = vm ? xvi : 0.f;
            u32 hb = f2bf(v);
            u32 lb = f2bf(v - bf2f((u16)hb));
            if (i & 1) { whi[i >> 1] |= hb << 16; wlo[i >> 1] |= lb << 16; }
            else       { whi[i >> 1]  = hb;       wlo[i >> 1]  = lb; }
        }
        *(uint4*)&Ah[buf][aoc * 72 + ak0] = pah;
        *(uint4*)&Al[buf][aoc * 72 + ak0] = pal;
        *(uint4*)&Bh[buf][nl * 72 + cl0] = make_uint4(whi[0], whi[1], whi[2], whi[3]);
        *(uint4*)&Bl[buf][nl * 72 + cl0] = make_uint4(wlo[0], wlo[1], wlo[2], wlo[3]);
    };

    // prologue: batch 0 loaded+stored; batch 1 issued, flies across barrier
    issue(0);
    WAITVM(0);
    stores(0);
    issue(1);
    asm volatile("s_waitcnt lgkmcnt(0)" ::: "memory");
    __builtin_amdgcn_s_barrier();
    __builtin_amdgcn_sched_barrier(0);

    for (int kt = 0; kt < 36; kt++) {
        int cur = kt & 1, nxt = kt + 1;
#pragma unroll
        for (int ks = 0; ks < 2; ks++) {
            int ko = ks * 32 + quad * 8;
            bf16x8 fah = *(const bf16x8*)&Ah[cur][(mt * 16 + col) * 72 + ko];
            bf16x8 fal = *(const bf16x8*)&Al[cur][(mt * 16 + col) * 72 + ko];
            bf16x8 fbh = *(const bf16x8*)&Bh[cur][(nt * 16 + col) * 72 + ko];
            bf16x8 fbl = *(const bf16x8*)&Bl[cur][(nt * 16 + col) * 72 + ko];
            acc = __builtin_amdgcn_mfma_f32_16x16x32_bf16(fah, fbh, acc, 0, 0, 0);
            acc = __builtin_amdgcn_mfma_f32_16x16x32_bf16(fah, fbl, acc, 0, 0, 0);
            acc = __builtin_amdgcn_mfma_f32_16x16x32_bf16(fal, fbh, acc, 0, 0, 0);
        }
        if (nxt < 36) {
            WAITVM(0);                           // batch nxt arrived (long window)
            stores(nxt & 1);                     // ds_write buf nxt&1
            if (nxt + 1 < 36) issue(nxt + 1);    // flies across the barrier
        }
        asm volatile("s_waitcnt lgkmcnt(0)" ::: "memory");  // my ds_writes done
        __builtin_amdgcn_s_barrier();            // RAW barrier: no vmcnt drain
        __builtin_amdgcn_sched_barrier(0);
    }

    int n = n0 + nt * 16 + col;
#pragma unroll
    for (int r = 0; r < 4; r++) {
        int oc = mt * 16 + quad * 4 + r;
        float s = acc[r];
        if (oc < 18) {
            int ch = 3 * (oc >> 1) + (oc & 1);   // even oc -> dy, odd -> dx
            offf[(ch << 14) + n] = s + boff[oc];
        } else if (oc < 27) {
            float tt = s + bmod[oc - 18];
            int ch = 3 * (oc - 18) + 2;
            offf[(ch << 14) + n] = 2.f / (1.f + __expf(-tt));
        }
    }
}

// ---------------------------------------------------------------------------
// Kernel 2 (FUSED): sampling + GEMM + BN + ReLU.  r13: 32 px/block, grid
// 512, LDS 72 KB -> 2 blocks/CU (16 waves). Each thread owns one (pixel,
// channel-quad): 4 gather dwordx4/kt, one tapcomp/tap, one uint2 Sl write.
// Wave MFMA tile 32o x 32n (acc[2][2], 8 MFMA/kt). Same per-pixel math,
// gather addresses, combine order, bf16 rounding as r10.
// ---------------------------------------------------------------------------
__global__ __launch_bounds__(512, 4) void kfused(const float* __restrict__ xt,
                                                 const float* __restrict__ offf,
                                                 const u16* __restrict__ wregb,
                                                 const float* __restrict__ gamma,
                                                 const float* __restrict__ beta,
                                                 const float* __restrict__ rmean,
                                                 const float* __restrict__ rvar,
                                                 float* __restrict__ out) {
    __shared__ u16 Wl[2][256 * 64];  // [buf][o][k] granule-XOR-swizzled, 64 KB
    __shared__ u16 Sl[2][8 * 32 * 8];// [buf][c-octet][px][8ch], 8 KB
    int tid = threadIdx.x;
    int lane = tid & 63, wv = tid >> 6;
    int chq = lane & 15;                         // channel-quad 0..15
    int plo = wv * 4 + (lane >> 4);              // own pixel 0..31
    // XCD swizzle: 512 blocks, xcd = bid&7 -> (img, band), j -> row/half
    int bid = blockIdx.x;
    int xcd = bid & 7, jj = bid >> 3;            // jj in [0,64)
    int bb  = xcd >> 1;                          // image   (block-uniform)
    int h   = ((xcd & 1) << 5) + (jj >> 1);      // row     (block-uniform)
    int nbase = ((bb << 6) + h) * 64 + (jj & 1) * 32;  // first pixel (32/block)
    int wo = wv * 32;                            // wave output tile 32o x 32n
    int col = lane & 15, quad = lane >> 4;

    const float* xb = xt + ((long)bb << 20);     // image base (SGPR)

    f32x4 acc[2][2];
#pragma unroll
    for (int i = 0; i < 2; i++)
#pragma unroll
        for (int j = 0; j < 2; j++) acc[i][j] = (f32x4){0.f, 0.f, 0.f, 0.f};

    u32   pb[4];                                 // neighbor record byte offs
    float sw[4];                                 // bilinear*mask weights
    f32x4 g[4];                                  // in-flight 4ch quads

    auto tapcomp = [&](int t) {                  // own pixel's tap state
        int n = nbase + plo;
        int w = n & 63;
        int gy = t / 3, tx = t - 3 * gy;
        float dy = offf[((3 * t + 0) << 14) + n];
        float dx = offf[((3 * t + 1) << 14) + n];
        float m  = offf[((3 * t + 2) << 14) + n];
        float py = (float)(h - 1 + gy) + dy;
        float px = (float)(w - 1 + tx) + dx;
        float y0f = floorf(py), x0f = floorf(px);
        float wy = py - y0f, wx = px - x0f;
        int iy0 = (int)y0f, ix0 = (int)x0f;
        int iy1 = iy0 + 1, ix1 = ix0 + 1;
        bool vy0 = (unsigned)iy0 < 64u, vy1 = (unsigned)iy1 < 64u;
        bool vx0 = (unsigned)ix0 < 64u, vx1 = (unsigned)ix1 < 64u;
        int cy0 = min(max(iy0, 0), 63), cy1 = min(max(iy1, 0), 63);
        int cx0 = min(max(ix0, 0), 63), cx1 = min(max(ix1, 0), 63);
        pb[0] = (u32)(cy0 * 64 + cx0) << 10; pb[1] = (u32)(cy0 * 64 + cx1) << 10;
        pb[2] = (u32)(cy1 * 64 + cx0) << 10; pb[3] = (u32)(cy1 * 64 + cx1) << 10;
        float a = 1.f - wy, bw = 1.f - wx;
        sw[0] = (vy0 && vx0) ? a  * bw * m : 0.f;
        sw[1] = (vy0 && vx1) ? a  * wx * m : 0.f;
        sw[2] = (vy1 && vx0) ? wy * bw * m : 0.f;
        sw[3] = (vy1 && vx1) ? wy * wx * m : 0.f;
    };
    auto gissue = [&](int kt) {                  // 4 dwordx4 (one per neighbor)
        u32 co = ((u32)(kt & 3) << 8) + (u32)chq * 16;
#pragma unroll
        for (int nb = 0; nb < 4; nb++) g[nb] = gload4f(xb, pb[nb] + co);
    };
    auto dmaA = [&](int kt, int buf) {           // async A staging, 32 KB
#pragma unroll
        for (int i = 0; i < 4; i++) {
            int cidx = tid + i * 512;
            int o = cidx >> 3, qp = cidx & 7;
            int ql = qp ^ (o & 7);               // source-side XOR swizzle
            load_lds16(wregb + (long)o * 2304 + kt * 64 + ql * 8,
                       &Wl[buf][cidx * 8]);
        }
    };
    auto bwrite = [&](int buf) {                 // combine + pack + 8B write
        f32x4 v = sw[0] * g[0] + sw[1] * g[1] + sw[2] * g[2] + sw[3] * g[3];
        u32 w0 = f2bf(v[0]) | (f2bf(v[1]) << 16);
        u32 w1 = f2bf(v[2]) | (f2bf(v[3]) << 16);
        *(uint2*)&Sl[buf][((chq >> 1) * 32 + plo) * 8 + (chq & 1) * 4] =
            make_uint2(w0, w1);
    };

    // prologue: fill buffer 0
    tapcomp(0);
    gissue(0);
    dmaA(0, 0);
    WAITVM(0);
    bwrite(0);
    __syncthreads();

    for (int kt = 0; kt < 36; kt++) {
        int cur = kt & 1, nxt = kt + 1;
        if (nxt < 36) {
            if ((nxt & 3) == 0) tapcomp(nxt >> 2);
            gissue(nxt);                         // 4 oldest outstanding vmem
            dmaA(nxt, nxt & 1);                  // 4 newest (drain at barrier)
        }
#pragma unroll
        for (int ks = 0; ks < 2; ks++) {
            bf16x8 af[2], bfr[2];
#pragma unroll
            for (int i = 0; i < 2; i++) {
                int r = wo + i * 16 + col;
                int ph = (ks * 4 + quad) ^ (r & 7);
                af[i] = *(const bf16x8*)&Wl[cur][r * 64 + ph * 8];
            }
#pragma unroll
            for (int j = 0; j < 2; j++)
                bfr[j] = *(const bf16x8*)&Sl[cur][((ks * 4 + quad) * 32 +
                                                   (j * 16 + col)) * 8];
#pragma unroll
            for (int i = 0; i < 2; i++)
#pragma unroll
                for (int j = 0; j < 2; j++)
                    acc[i][j] = __builtin_amdgcn_mfma_f32_16x16x32_bf16(
                        af[i], bfr[j], acc[i][j], 0, 0, 0);
        }
        if (nxt < 36) {
            WAITVM(4);                           // gathers done, DMA may fly
            bwrite(nxt & 1);
        }
        __syncthreads();                         // drains DMA + ds_write; one/kt
    }

    // epilogue: BN + ReLU, D layout: row(o) = quad*4+reg, col(n) = lane&15
#pragma unroll
    for (int i = 0; i < 2; i++) {
        int ob = wo + i * 16 + quad * 4;
        float inv[4], add[4];
#pragma unroll
        for (int r = 0; r < 4; r++) {
            int o = ob + r;
            float iv = gamma[o] * rsqrtf(rvar[o] + 1e-5f);
            inv[r] = iv; add[r] = beta[o] - rmean[o] * iv;
        }
#pragma unroll
        for (int j = 0; j < 2; j++) {
            int n_g = nbase + j * 16 + col;
            int bq = n_g >> 12, hw = n_g & 4095;
            float* op = out + ((long)bq << 20) + hw;
#pragma unroll
            for (int r = 0; r < 4; r++) {
                float v = acc[i][j][r] * inv[r] + add[r];
                v = fmaxf(v, 0.f);
                op[(long)(ob + r) << 12] = v;
            }
        }
    }
}

// ---------------------------------------------------------------------------
extern "C" void kernel_launch(void* const* d_in, const int* in_sizes, int n_in,
                              void* d_out, int out_size, void* d_ws, size_t ws_size,
                              hipStream_t stream) {
    const float* x     = (const float*)d_in[0];
    const float* woff  = (const float*)d_in[1];
    const float* boff  = (const float*)d_in[2];
    const float* wmod  = (const float*)d_in[3];
    const float* bmod  = (const float*)d_in[4];
    const float* wreg  = (const float*)d_in[5];
    const float* gamma = (const float*)d_in[6];
    const float* beta  = (const float*)d_in[7];
    const float* rmean = (const float*)d_in[8];
    const float* rvar  = (const float*)d_in[9];
    float* out = (float*)d_out;

    char* ws = (char*)d_ws;
    // ws map:
    //   [0x000000, 0x024000)  wph   bf16  144 KB (A hi, koffg)
    //   [0x040000, 0x064000)  wpl   bf16  144 KB (A lo)
    //   [0x080000, 0x23C000)  offf  fp32  1.77 MB
    //   [0x240000, 0x360000)  wregb bf16  1.18 MB ([o][t*256+c] order)
    //   [0x400000, 0x1400000) xt    fp32  16 MB  (channel-last x)
    u16*   wph   = (u16*)(ws);
    u16*   wpl   = (u16*)(ws + 0x40000u);
    float* offf  = (float*)(ws + 0x80000u);
    u16*   wregb = (u16*)(ws + 0x240000u);
    float* xt    = (float*)(ws + 0x400000u);

    kprep<<<288,  256, 0, stream>>>(woff, wmod, wph, wpl);
    kwreg<<<2304, 256, 0, stream>>>(wreg, wregb);
    ktrans<<<dim3(64, 4, 4), 256, 0, stream>>>(x, xt);
    koffg<<<512,  256, 0, stream>>>(xt, wph, wpl, boff, bmod, offf);
    kfused<<<512, 512, 0, stream>>>(xt, offf, wregb, gamma, beta,
                                    rmean, rvar, out);
}

// Round 14
// 175.131 us; speedup vs baseline: 1.4189x; 1.0193x over previous
//
#include <hip/hip_runtime.h>
#include <hip/hip_bf16.h>

typedef unsigned short u16;
typedef unsigned int   u32;
typedef short   bf16x8 __attribute__((ext_vector_type(8)));  // bf16 carried as i16
typedef float   f32x4  __attribute__((ext_vector_type(4)));

__device__ __forceinline__ float bf2f(u16 u) {
    u32 t = ((u32)u) << 16;
    return __builtin_bit_cast(float, t);
}
__device__ __forceinline__ u32 f2bf(float f) {
    u32 u = __builtin_bit_cast(u32, f);
    return (u + 0x7FFFu + ((u >> 16) & 1u)) >> 16;   // RNE
}
// async global->LDS DMA, 16 B per lane (dst = wave-uniform base + lane*16)
__device__ __forceinline__ void load_lds16(const u16* g, u16* l) {
    __builtin_amdgcn_global_load_lds(
        (const __attribute__((address_space(1))) u32*)(const void*)g,
        (__attribute__((address_space(3))) u32*)(void*)l, 16, 0, 0);
}
// Inline-asm loads (saddr form): compiler cannot sink these or auto-wait on
// them -> true async issue, paired with manual vmcnt (rule #18).
// ALL loads 16B-aligned dwordx4 (no alignment hazards).
__device__ __forceinline__ uint4 gload4(const u16* sbase, u32 voff) {
    uint4 r;
    asm volatile("global_load_dwordx4 %0, %1, %2"
                 : "=v"(r) : "v"(voff), "s"(sbase) : "memory");
    return r;
}
__device__ __forceinline__ f32x4 gload4f(const float* sbase, u32 voff) {
    f32x4 r;
    asm volatile("global_load_dwordx4 %0, %1, %2"
                 : "=v"(r) : "v"(voff), "s"(sbase) : "memory");
    return r;
}
#define WAITVM(N) do { asm volatile("s_waitcnt vmcnt(" #N ")" ::: "memory"); \
                       __builtin_amdgcn_sched_barrier(0); } while (0)

// ---------------------------------------------------------------------------
// GLOBAL K-ORDER (both GEMMs): r = t*256 + c  (tap-major).
// XCD swizzle (verified r6): xcd = bid&7 -> 32-row band of one image.
// Channel-last xt[b][pixel][c] (r8). Divergence-aware gather lane maps:
// kfused (r9/r10: 104.6 -> 67.8us), koffg (r14, this round — same remap:
// wave = 4 px-slots x 16 ch-quads, 16-lane groups read 256B contiguous of
// one pixel record -> 16 cachelines/wave-instr instead of 64).
// koffg T4 raw-barrier (r12). kfused 2-blocks/CU (r13: 75 -> 62us).
// ---------------------------------------------------------------------------

// Kernel 0a: offset/mask conv weights -> hi/lo bf16 A[32][2304], r = t*256+c
__global__ void kprep(const float* __restrict__ woff, const float* __restrict__ wmod,
                      u16* __restrict__ ah, u16* __restrict__ al) {
    int i = blockIdx.x * 256 + threadIdx.x;      // 288 blocks -> 73728 exact
    if (i >= 32 * 2304) return;
    int oc = i / 2304, r = i - oc * 2304;
    int t = r >> 8, c = r & 255;
    float v = 0.f;
    if (oc < 18)      v = woff[oc * 2304 + c * 9 + t];
    else if (oc < 27) v = wmod[(oc - 18) * 2304 + c * 9 + t];
    u32 hb = f2bf(v);
    u32 lb = f2bf(v - bf2f((u16)hb));
    ah[i] = (u16)hb;
    al[i] = (u16)lb;
}

// Kernel 0b: w_reg f32 -> bf16, layout [o][t*256+c] (matches gather K-order).
__global__ void kwreg(const float* __restrict__ wreg, u16* __restrict__ wregb) {
    int i = blockIdx.x * 256 + threadIdx.x;      // 2304 blocks exact
    int o = i / 2304, r = i - o * 2304;
    int t = r >> 8, c = r & 255;
    wregb[i] = (u16)f2bf(wreg[o * 2304 + c * 9 + t]);
}

// Kernel 0c: transpose x[b][c][p] -> xt[b][p][c]  (channel-last, 16 MB).
__global__ __launch_bounds__(256) void ktrans(const float* __restrict__ x,
                                              float* __restrict__ xt) {
    __shared__ float T[64][65];
    int t = threadIdx.x;
    int pl = t & 63, cr = t >> 6;                // 4 rows per pass
    int p0 = blockIdx.x * 64;                    // pixel tile
    int c0 = blockIdx.y * 64;                    // channel tile
    int b  = blockIdx.z;
    const float* xb  = x  + ((long)b << 20);
    float*       xtb = xt + ((long)b << 20);
#pragma unroll
    for (int i = 0; i < 16; i++) {
        int c = cr + i * 4;
        T[c][pl] = xb[((long)(c0 + c) << 12) + p0 + pl];
    }
    __syncthreads();
#pragma unroll
    for (int i = 0; i < 16; i++) {
        int p = cr + i * 4;
        xtb[(long)(p0 + p) * 256 + c0 + pl] = T[pl][p];
    }
}

// ---------------------------------------------------------------------------
// Kernel 1: offset/mask conv as MFMA GEMM, M=32 (27 live), N=16384, K=2304.
// r14: B-staging lane remap (divergence-aware). Wave = 4 px-slots x 16
// ch-quads; thread loads one dwordx4 (4 ch) for px0 = wv*4+slot and px1 =
// px0+16 -> 16 cachelines/wave-instr (was 64: nl=tid&31 put 64 records in
// one instr). LDS Bh/Bl content byte-identical (uint2 at px*72+chq*4);
// MFMA reads and r12 T4 raw-barrier loop unchanged.
// ---------------------------------------------------------------------------
__global__ __launch_bounds__(256) void koffg(const float* __restrict__ xt,
                                             const u16* __restrict__ ah_g,
                                             const u16* __restrict__ al_g,
                                             const float* __restrict__ boff,
                                             const float* __restrict__ bmod,
                                             float* __restrict__ offf) {
    __shared__ u16 Ah[2][32 * 72], Al[2][32 * 72]; // 32 oc-rows, 64 k + 8 pad
    __shared__ u16 Bh[2][32 * 72], Bl[2][32 * 72]; // 32 px-rows, 64 k + 8 pad
    int tid = threadIdx.x;
    // XCD swizzle: 512 blocks, xcd = bid&7 -> (img, band), j -> row/half
    int bid = blockIdx.x;
    int xcd = bid & 7, j = bid >> 3;             // j in [0,64)
    int img = xcd >> 1;
    int row = ((xcd & 1) << 5) + (j >> 1);
    int n0 = ((img << 6) + row) * 64 + (j & 1) * 32;
    int b = n0 >> 12, h0 = (n0 & 4095) >> 6, w0 = n0 & 63;
    int lane = tid & 63, wv = tid >> 6;
    int mt = wv & 1, nt = wv >> 1;               // 2 m-tiles x 2 n-tiles of 16
    int col = lane & 15, quad = lane >> 4;

    int aoc = tid >> 3, ak0 = (tid & 7) * 8;     // A staging role (unchanged)
    int chq = lane & 15, pxs = lane >> 4;        // B staging: ch-quad, px-slot
    int px0 = wv * 4 + pxs, px1 = px0 + 16;      // own pixels (0..15, 16..31)

    const float* xtb = xt + ((long)b << 20);     // image base (SGPR)
    u32 avoff0 = (u32)(aoc * 2304 + ak0) * 2;    // bytes into ah_g/al_g

    f32x4 acc = (f32x4){0.f, 0.f, 0.f, 0.f};

    uint4 pah, pal;
    f32x4 xa, xc;                                // px0 / px1 channel quads
    bool  vma, vmb;

    auto issue = [&](int kt) {                   // 4 asm loads, stay in flight
        int t = kt >> 2, c0 = (kt & 3) << 6, r0 = kt * 64;
        int dy = t / 3 - 1, dx = t % 3 - 1;
        pah = gload4(ah_g, avoff0 + (u32)r0 * 2);
        pal = gload4(al_g, avoff0 + (u32)r0 * 2);
        int hp = h0 + dy;
        bool vh = (unsigned)hp < 64u;
        int hc = min(max(hp, 0), 63);
        u32 cb = (u32)(c0 + chq * 4) << 2;       // channel byte offset (16B-al)
        int wpa = w0 + px0 + dx;
        vma = vh && ((unsigned)wpa < 64u);
        int wca = min(max(wpa, 0), 63);
        xa = gload4f(xtb, ((u32)(hc * 64 + wca) << 10) + cb);
        int wpb = w0 + px1 + dx;
        vmb = vh && ((unsigned)wpb < 64u);
        int wcb = min(max(wpb, 0), 63);
        xc = gload4f(xtb, ((u32)(hc * 64 + wcb) << 10) + cb);
    };
    auto stores = [&](int buf) {                 // after WAITVM(0); buf in {0,1}
        *(uint4*)&Ah[buf][aoc * 72 + ak0] = pah;
        *(uint4*)&Al[buf][aoc * 72 + ak0] = pal;
        u32 wh[2], wl[2];
#pragma unroll
        for (int i = 0; i < 4; i++) {
            float v = vma ? xa[i] : 0.f;
            u32 hb = f2bf(v);
            u32 lb = f2bf(v - bf2f((u16)hb));
            if (i & 1) { wh[i >> 1] |= hb << 16; wl[i >> 1] |= lb << 16; }
            else       { wh[i >> 1]  = hb;       wl[i >> 1]  = lb; }
        }
        *(uint2*)&Bh[buf][px0 * 72 + chq * 4] = make_uint2(wh[0], wh[1]);
        *(uint2*)&Bl[buf][px0 * 72 + chq * 4] = make_uint2(wl[0], wl[1]);
#pragma unroll
        for (int i = 0; i < 4; i++) {
            float v = vmb ? xc[i] : 0.f;
            u32 hb = f2bf(v);
            u32 lb = f2bf(v - bf2f((u16)hb));
            if (i & 1) { wh[i >> 1] |= hb << 16; wl[i >> 1] |= lb << 16; }
            else       { wh[i >> 1]  = hb;       wl[i >> 1]  = lb; }
        }
        *(uint2*)&Bh[buf][px1 * 72 + chq * 4] = make_uint2(wh[0], wh[1]);
        *(uint2*)&Bl[buf][px1 * 72 + chq * 4] = make_uint2(wl[0], wl[1]);
    };

    // prologue: batch 0 loaded+stored; batch 1 issued, flies across barrier
    issue(0);
    WAITVM(0);
    stores(0);
    issue(1);
    asm volatile("s_waitcnt lgkmcnt(0)" ::: "memory");
    __builtin_amdgcn_s_barrier();
    __builtin_amdgcn_sched_barrier(0);

    for (int kt = 0; kt < 36; kt++) {
        int cur = kt & 1, nxt = kt + 1;
#pragma unroll
        for (int ks = 0; ks < 2; ks++) {
            int ko = ks * 32 + quad * 8;
            bf16x8 fah = *(const bf16x8*)&Ah[cur][(mt * 16 + col) * 72 + ko];
            bf16x8 fal = *(const bf16x8*)&Al[cur][(mt * 16 + col) * 72 + ko];
            bf16x8 fbh = *(const bf16x8*)&Bh[cur][(nt * 16 + col) * 72 + ko];
            bf16x8 fbl = *(const bf16x8*)&Bl[cur][(nt * 16 + col) * 72 + ko];
            acc = __builtin_amdgcn_mfma_f32_16x16x32_bf16(fah, fbh, acc, 0, 0, 0);
            acc = __builtin_amdgcn_mfma_f32_16x16x32_bf16(fah, fbl, acc, 0, 0, 0);
            acc = __builtin_amdgcn_mfma_f32_16x16x32_bf16(fal, fbh, acc, 0, 0, 0);
        }
        if (nxt < 36) {
            WAITVM(0);                           // batch nxt arrived (long window)
            stores(nxt & 1);                     // ds_write buf nxt&1
            if (nxt + 1 < 36) issue(nxt + 1);    // flies across the barrier
        }
        asm volatile("s_waitcnt lgkmcnt(0)" ::: "memory");  // my ds_writes done
        __builtin_amdgcn_s_barrier();            // RAW barrier: no vmcnt drain
        __builtin_amdgcn_sched_barrier(0);
    }

    int n = n0 + nt * 16 + col;
#pragma unroll
    for (int r = 0; r < 4; r++) {
        int oc = mt * 16 + quad * 4 + r;
        float s = acc[r];
        if (oc < 18) {
            int ch = 3 * (oc >> 1) + (oc & 1);   // even oc -> dy, odd -> dx
            offf[(ch << 14) + n] = s + boff[oc];
        } else if (oc < 27) {
            float tt = s + bmod[oc - 18];
            int ch = 3 * (oc - 18) + 2;
            offf[(ch << 14) + n] = 2.f / (1.f + __expf(-tt));
        }
    }
}

// ---------------------------------------------------------------------------
// Kernel 2 (FUSED): sampling + GEMM + BN + ReLU.  r13-EXACT (verified
// 61.9 us, occupancy 35%): 32 px/block, grid 512, 2 blocks/CU, divergence-
// aware gathers. Queued: Sl write bank-conflict swizzle (4.13M conflicts).
// ---------------------------------------------------------------------------
__global__ __launch_bounds__(512, 4) void kfused(const float* __restrict__ xt,
                                                 const float* __restrict__ offf,
                                                 const u16* __restrict__ wregb,
                                                 const float* __restrict__ gamma,
                                                 const float* __restrict__ beta,
                                                 const float* __restrict__ rmean,
                                                 const float* __restrict__ rvar,
                                                 float* __restrict__ out) {
    __shared__ u16 Wl[2][256 * 64];  // [buf][o][k] granule-XOR-swizzled, 64 KB
    __shared__ u16 Sl[2][8 * 32 * 8];// [buf][c-octet][px][8ch], 8 KB
    int tid = threadIdx.x;
    int lane = tid & 63, wv = tid >> 6;
    int chq = lane & 15;                         // channel-quad 0..15
    int plo = wv * 4 + (lane >> 4);              // own pixel 0..31
    // XCD swizzle: 512 blocks, xcd = bid&7 -> (img, band), j -> row/half
    int bid = blockIdx.x;
    int xcd = bid & 7, jj = bid >> 3;            // jj in [0,64)
    int bb  = xcd >> 1;                          // image   (block-uniform)
    int h   = ((xcd & 1) << 5) + (jj >> 1);      // row     (block-uniform)
    int nbase = ((bb << 6) + h) * 64 + (jj & 1) * 32;  // first pixel (32/block)
    int wo = wv * 32;                            // wave output tile 32o x 32n
    int col = lane & 15, quad = lane >> 4;

    const float* xb = xt + ((long)bb << 20);     // image base (SGPR)

    f32x4 acc[2][2];
#pragma unroll
    for (int i = 0; i < 2; i++)
#pragma unroll
        for (int j = 0; j < 2; j++) acc[i][j] = (f32x4){0.f, 0.f, 0.f, 0.f};

    u32   pb[4];                                 // neighbor record byte offs
    float sw[4];                                 // bilinear*mask weights
    f32x4 g[4];                                  // in-flight 4ch quads

    auto tapcomp = [&](int t) {                  // own pixel's tap state
        int n = nbase + plo;
        int w = n & 63;
        int gy = t / 3, tx = t - 3 * gy;
        float dy = offf[((3 * t + 0) << 14) + n];
        float dx = offf[((3 * t + 1) << 14) + n];
        float m  = offf[((3 * t + 2) << 14) + n];
        float py = (float)(h - 1 + gy) + dy;
        float px = (float)(w - 1 + tx) + dx;
        float y0f = floorf(py), x0f = floorf(px);
        float wy = py - y0f, wx = px - x0f;
        int iy0 = (int)y0f, ix0 = (int)x0f;
        int iy1 = iy0 + 1, ix1 = ix0 + 1;
        bool vy0 = (unsigned)iy0 < 64u, vy1 = (unsigned)iy1 < 64u;
        bool vx0 = (unsigned)ix0 < 64u, vx1 = (unsigned)ix1 < 64u;
        int cy0 = min(max(iy0, 0), 63), cy1 = min(max(iy1, 0), 63);
        int cx0 = min(max(ix0, 0), 63), cx1 = min(max(ix1, 0), 63);
        pb[0] = (u32)(cy0 * 64 + cx0) << 10; pb[1] = (u32)(cy0 * 64 + cx1) << 10;
        pb[2] = (u32)(cy1 * 64 + cx0) << 10; pb[3] = (u32)(cy1 * 64 + cx1) << 10;
        float a = 1.f - wy, bw = 1.f - wx;
        sw[0] = (vy0 && vx0) ? a  * bw * m : 0.f;
        sw[1] = (vy0 && vx1) ? a  * wx * m : 0.f;
        sw[2] = (vy1 && vx0) ? wy * bw * m : 0.f;
        sw[3] = (vy1 && vx1) ? wy * wx * m : 0.f;
    };
    auto gissue = [&](int kt) {                  // 4 dwordx4 (one per neighbor)
        u32 co = ((u32)(kt & 3) << 8) + (u32)chq * 16;
#pragma unroll
        for (int nb = 0; nb < 4; nb++) g[nb] = gload4f(xb, pb[nb] + co);
    };
    auto dmaA = [&](int kt, int buf) {           // async A staging, 32 KB
#pragma unroll
        for (int i = 0; i < 4; i++) {
            int cidx = tid + i * 512;
            int o = cidx >> 3, qp = cidx & 7;
            int ql = qp ^ (o & 7);               // source-side XOR swizzle
            load_lds16(wregb + (long)o * 2304 + kt * 64 + ql * 8,
                       &Wl[buf][cidx * 8]);
        }
    };
    auto bwrite = [&](int buf) {                 // combine + pack + 8B write
        f32x4 v = sw[0] * g[0] + sw[1] * g[1] + sw[2] * g[2] + sw[3] * g[3];
        u32 w0 = f2bf(v[0]) | (f2bf(v[1]) << 16);
        u32 w1 = f2bf(v[2]) | (f2bf(v[3]) << 16);
        *(uint2*)&Sl[buf][((chq >> 1) * 32 + plo) * 8 + (chq & 1) * 4] =
            make_uint2(w0, w1);
    };

    // prologue: fill buffer 0
    tapcomp(0);
    gissue(0);
    dmaA(0, 0);
    WAITVM(0);
    bwrite(0);
    __syncthreads();

    for (int kt = 0; kt < 36; kt++) {
        int cur = kt & 1, nxt = kt + 1;
        if (nxt < 36) {
            if ((nxt & 3) == 0) tapcomp(nxt >> 2);
            gissue(nxt);                         // 4 oldest outstanding vmem
            dmaA(nxt, nxt & 1);                  // 4 newest (drain at barrier)
        }
#pragma unroll
        for (int ks = 0; ks < 2; ks++) {
            bf16x8 af[2], bfr[2];
#pragma unroll
            for (int i = 0; i < 2; i++) {
                int r = wo + i * 16 + col;
                int ph = (ks * 4 + quad) ^ (r & 7);
                af[i] = *(const bf16x8*)&Wl[cur][r * 64 + ph * 8];
            }
#pragma unroll
            for (int j = 0; j < 2; j++)
                bfr[j] = *(const bf16x8*)&Sl[cur][((ks * 4 + quad) * 32 +
                                                   (j * 16 + col)) * 8];
#pragma unroll
            for (int i = 0; i < 2; i++)
#pragma unroll
                for (int j = 0; j < 2; j++)
                    acc[i][j] = __builtin_amdgcn_mfma_f32_16x16x32_bf16(
                        af[i], bfr[j], acc[i][j], 0, 0, 0);
        }
        if (nxt < 36) {
            WAITVM(4);                           // gathers done, DMA may fly
            bwrite(nxt & 1);
        }
        __syncthreads();                         // drains DMA + ds_write; one/kt
    }

    // epilogue: BN + ReLU, D layout: row(o) = quad*4+reg, col(n) = lane&15
#pragma unroll
    for (int i = 0; i < 2; i++) {
        int ob = wo + i * 16 + quad * 4;
        float inv[4], add[4];
#pragma unroll
        for (int r = 0; r < 4; r++) {
            int o = ob + r;
            float iv = gamma[o] * rsqrtf(rvar[o] + 1e-5f);
            inv[r] = iv; add[r] = beta[o] - rmean[o] * iv;
        }
#pragma unroll
        for (int j = 0; j < 2; j++) {
            int n_g = nbase + j * 16 + col;
            int bq = n_g >> 12, hw = n_g & 4095;
            float* op = out + ((long)bq << 20) + hw;
#pragma unroll
            for (int r = 0; r < 4; r++) {
                float v = acc[i][j][r] * inv[r] + add[r];
                v = fmaxf(v, 0.f);
                op[(long)(ob + r) << 12] = v;
            }
        }
    }
}

// ---------------------------------------------------------------------------
extern "C" void kernel_launch(void* const* d_in, const int* in_sizes, int n_in,
                              void* d_out, int out_size, void* d_ws, size_t ws_size,
                              hipStream_t stream) {
    const float* x     = (const float*)d_in[0];
    const float* woff  = (const float*)d_in[1];
    const float* boff  = (const float*)d_in[2];
    const float* wmod  = (const float*)d_in[3];
    const float* bmod  = (const float*)d_in[4];
    const float* wreg  = (const float*)d_in[5];
    const float* gamma = (const float*)d_in[6];
    const float* beta  = (const float*)d_in[7];
    const float* rmean = (const float*)d_in[8];
    const float* rvar  = (const float*)d_in[9];
    float* out = (float*)d_out;

    char* ws = (char*)d_ws;
    // ws map:
    //   [0x000000, 0x024000)  wph   bf16  144 KB (A hi, koffg)
    //   [0x040000, 0x064000)  wpl   bf16  144 KB (A lo)
    //   [0x080000, 0x23C000)  offf  fp32  1.77 MB
    //   [0x240000, 0x360000)  wregb bf16  1.18 MB ([o][t*256+c] order)
    //   [0x400000, 0x1400000) xt    fp32  16 MB  (channel-last x)
    u16*   wph   = (u16*)(ws);
    u16*   wpl   = (u16*)(ws + 0x40000u);
    float* offf  = (float*)(ws + 0x80000u);
    u16*   wregb = (u16*)(ws + 0x240000u);
    float* xt    = (float*)(ws + 0x400000u);

    kprep<<<288,  256, 0, stream>>>(woff, wmod, wph, wpl);
    kwreg<<<2304, 256, 0, stream>>>(wreg, wregb);
    ktrans<<<dim3(64, 4, 4), 256, 0, stream>>>(x, xt);
    koffg<<<512,  256, 0, stream>>>(xt, wph, wpl, boff, bmod, offf);
    kfused<<<512, 512, 0, stream>>>(xt, offf, wregb, gamma, beta,
                                    rmean, rvar, out);
}